// Round 3
// baseline (4908.031 us; speedup 1.0000x reference)
//
#include <hip/hip_runtime.h>
#include <hip/hip_bf16.h>

#define NB 8192
#define SROW 391

// ---- weight ws layout (floats) ----
#define TW      22848
#define W_WIH   0
#define W_WHH   1536
#define W_BSUM  17920
#define W_WTS   18176
#define W_BTS   22272
#define W_WOS   22336
#define W_BOS   22784
#define W_OUT   68544
#define WO_WIHO 0
#define WO_WHHO 32768
#define WO_BSUM 49152
#define WO_W1   49408
#define WO_B1   53504
#define WO_W2   53568
#define WO_B2   54144
#define WF_TOTAL 122697

typedef unsigned short u16;

__device__ __forceinline__ float bf2f(u16 u){ return __uint_as_float(((unsigned)u) << 16); }
__device__ __forceinline__ u16 f2bf(float f){
  unsigned x = __float_as_uint(f);
  unsigned r = (x + 0x7FFFu + ((x >> 16) & 1u)) >> 16;   // RNE
  return (u16)r;
}
// fast-math-immune NaN test on f32 bits
__device__ __forceinline__ bool isnanf32(float f){
  unsigned x = __float_as_uint(f);
  return (x & 0x7FFFFFFFu) > 0x7F800000u;
}
// dtype-dispatched input load (element index)
__device__ __forceinline__ float ldin(const void* p, size_t i, bool isbf){
  if (isbf) return bf2f(((const u16*)p)[i]);
  return ((const float*)p)[i];
}
__device__ __forceinline__ float sigm(float x){ return 1.0f / (1.0f + expf(-x)); }

struct Seg { int src; int src2; int dst; int n; };
struct SegTab { Seg s[28]; };
struct PtrTab { const void* p[36]; };

// ---------- kernel D: detect input dtype from Whh0 bit patterns ----------
__global__ void kdetect(const void* whh0, int* flag){
  if (threadIdx.x == 0 && blockIdx.x == 0){
    const u16* u = (const u16*)whh0;
    int cnt = 0;
    for (int i = 0; i < 128; i += 2){            // even u16s: bf16 values OR f32 low-mantissa halves
      int e = (u[i] >> 7) & 0xFF;
      cnt += (e >= 100 && e <= 141) ? 1 : 0;     // plausible bf16 exponent for N(0,0.1) data
    }
    *flag = (cnt >= 32) ? 1 : 0;                 // bf16 ~64/64 hits; f32 ~10/64
  }
}

// ---------- kernel W: convert weights -> fp32 into ws ----------
__global__ __launch_bounds__(256) void kweights(PtrTab P, SegTab S, float* __restrict__ WF,
                                                const int* __restrict__ flag){
  const bool isbf = (*flag != 0);
  Seg sg = S.s[blockIdx.x];
  const void* a = P.p[sg.src];
  const void* b = (sg.src2 >= 0) ? P.p[sg.src2] : nullptr;
  for (int i = threadIdx.x; i < sg.n; i += 256){
    float v = ldin(a, i, isbf);
    if (b) v += ldin(b, i, isbf);
    WF[sg.dst + i] = v;
  }
}

// ---------- kernel M: inner LSTM (64 steps) + xOS + xTS. wave q = gate type, lane = batch ----------
__global__ __launch_bounds__(256) void kmain(const void* __restrict__ s,
                                             const void* __restrict__ sh,
                                             const int* __restrict__ hist_len,
                                             const float* __restrict__ WF,
                                             u16* __restrict__ xpart,
                                             const int* __restrict__ flag){
  __shared__ float g_lds[4][64][64];   // 64 KB; g_lds[0] doubles as h-exchange
  const bool isbf = (*flag != 0);
  const int t  = blockIdx.y;
  const int bl = threadIdx.x & 63;
  const int q  = threadIdx.x >> 6;
  const int b  = blockIdx.x * 64 + bl;
  const int hl = hist_len[b];

  // always-valid base + element offset + zero flag (no null derefs)
  const void* base; size_t soff; float zf;
  if (t == 0){ base = s;  soff = (size_t)b * SROW; zf = 1.0f; }
  else {
    base = sh; soff = ((size_t)b * 2 + ((t == 1) ? 1 : 0)) * SROW;
    zf = (hl == 2) ? 1.0f : 0.0f;
  }

  const float* Wt   = WF + t * TW;
  const float* wih  = Wt + W_WIH;
  const float* whh  = Wt + W_WHH;
  const float* bsum = Wt + W_BSUM;
  const float* wts  = Wt + W_WTS;
  const float* bts  = Wt + W_BTS;
  const float* wos  = Wt + W_WOS;
  const float* bos  = Wt + W_BOS;

  float hreg[64], hown[16], creg[16];
  #pragma unroll
  for (int k = 0; k < 64; ++k) hreg[k] = 0.0f;
  #pragma unroll
  for (int k = 0; k < 16; ++k){ hown[k] = 0.0f; creg[k] = 0.0f; }

  for (int step = 0; step < 64; ++step){
    // valid rows form a prefix; freeze <=> first feature of row is NaN (and zf!=0)
    float f0 = ldin(base, soff + 7 + 6 * step, isbf);
    const bool rowvalid = (zf == 0.0f) || !isnanf32(f0);
    float sv[6];
    #pragma unroll
    for (int i = 0; i < 6; ++i){
      float f = ldin(base, soff + 7 + 6 * step + i, isbf);
      sv[i] = isnanf32(f) ? 0.0f : f * zf;
    }

    // gates: wave q computes rows q*64 + j
    for (int j = 0; j < 64; ++j){
      const int row = q * 64 + j;
      float acc = bsum[row];
      const float* wr = wih + row * 6;
      #pragma unroll
      for (int i = 0; i < 6; ++i) acc = fmaf(wr[i], sv[i], acc);
      const float* wh = whh + row * 64;
      #pragma unroll
      for (int k = 0; k < 64; ++k) acc = fmaf(wh[k], hreg[k], acc);
      float a = (q == 2) ? tanhf(acc) : sigm(acc);
      g_lds[q][j][bl] = a;
    }
    __syncthreads();

    // update: wave q owns units [q*16, q*16+16). Static private indexing only.
    #pragma unroll
    for (int jj = 0; jj < 16; ++jj){
      const int j = q * 16 + jj;
      float si = g_lds[0][j][bl];
      float sf = g_lds[1][j][bl];
      float tg = g_lds[2][j][bl];
      float so = g_lds[3][j][bl];
      float c  = sf * creg[jj] + si * tg;
      float hn = so * tanhf(c);
      creg[jj] = rowvalid ? c  : creg[jj];
      hown[jj] = rowvalid ? hn : hown[jj];
    }
    __syncthreads();   // gate reads done; g_lds[0] free for h exchange

    #pragma unroll
    for (int jj = 0; jj < 16; ++jj) g_lds[0][q * 16 + jj][bl] = hown[jj];
    __syncthreads();

    #pragma unroll
    for (int k = 0; k < 64; ++k) hreg[k] = g_lds[0][k][bl];
    __syncthreads();   // h reads done before next step's wave-0 gate writes
  }

  // epilogue: xTS = relu(WTS @ h + bTS), xOS = relu(WOS @ sOS + bOS)
  #pragma unroll
  for (int jj = 0; jj < 16; ++jj){
    const int j = q * 16 + jj;
    float acc = bts[j];
    const float* wr = wts + j * 64;
    #pragma unroll
    for (int k = 0; k < 64; ++k) acc = fmaf(wr[k], hreg[k], acc);
    xpart[((size_t)(t * 128 + 64 + j)) * NB + b] = f2bf(fmaxf(acc, 0.0f));

    float ao = bos[j];
    const float* wo = wos + j * 7;
    #pragma unroll
    for (int i = 0; i < 7; ++i) ao = fmaf(wo[i], ldin(base, soff + i, isbf) * zf, ao);
    xpart[((size_t)(t * 128 + j)) * NB + b] = f2bf(fmaxf(ao, 0.0f));
  }
}

// ---------- kernel F: outer LSTM (3 steps, Wiho@x inline) + MLP ----------
__global__ __launch_bounds__(256) void kfinal(const float* __restrict__ WF,
                                              const u16* __restrict__ xpart,
                                              const int* __restrict__ hist_len,
                                              void* __restrict__ out,
                                              const int* __restrict__ flag){
  __shared__ float g_lds[4][64][64];   // 64 KB
  const bool isbf = (*flag != 0);
  const int bl = threadIdx.x & 63;
  const int q  = threadIdx.x >> 6;
  const int b  = blockIdx.x * 64 + bl;
  const int hl = hist_len[b];

  const float* WO    = WF + W_OUT;
  const float* wiho  = WO + WO_WIHO;
  const float* whho  = WO + WO_WHHO;
  const float* bsumo = WO + WO_BSUM;
  const float* w1    = WO + WO_W1;
  const float* b1v   = WO + WO_B1;
  const float* w2    = WO + WO_W2;
  const float* b2v   = WO + WO_B2;

  float hreg[64], hown[16], creg[16];
  #pragma unroll
  for (int k = 0; k < 64; ++k) hreg[k] = 0.0f;
  #pragma unroll
  for (int k = 0; k < 16; ++k){ hown[k] = 0.0f; creg[k] = 0.0f; }

  for (int p = 0; p < 3; ++p){
    const int tt = 2 - ((p - hl + 2) % 3);   // which inner output feeds step p
    const u16* xb = xpart + (size_t)(tt * 128) * NB + b;
    const bool rowvalid = (p <= hl);         // hidden = hs[hist_len]

    float xv[128];
    #pragma unroll
    for (int i = 0; i < 128; ++i) xv[i] = bf2f(xb[(size_t)i * NB]);

    for (int j = 0; j < 64; ++j){
      const int row = q * 64 + j;
      float acc = bsumo[row];
      const float* wi = wiho + row * 128;
      #pragma unroll
      for (int i = 0; i < 128; ++i) acc = fmaf(wi[i], xv[i], acc);
      const float* wh = whho + row * 64;
      #pragma unroll
      for (int k = 0; k < 64; ++k) acc = fmaf(wh[k], hreg[k], acc);
      float a = (q == 2) ? tanhf(acc) : sigm(acc);
      g_lds[q][j][bl] = a;
    }
    __syncthreads();

    #pragma unroll
    for (int jj = 0; jj < 16; ++jj){
      const int j = q * 16 + jj;
      float si = g_lds[0][j][bl];
      float sf = g_lds[1][j][bl];
      float tg = g_lds[2][j][bl];
      float so = g_lds[3][j][bl];
      float c  = sf * creg[jj] + si * tg;
      float hn = so * tanhf(c);
      creg[jj] = rowvalid ? c  : creg[jj];
      hown[jj] = rowvalid ? hn : hown[jj];
    }
    __syncthreads();

    #pragma unroll
    for (int jj = 0; jj < 16; ++jj) g_lds[0][q * 16 + jj][bl] = hown[jj];
    __syncthreads();

    #pragma unroll
    for (int k = 0; k < 64; ++k) hreg[k] = g_lds[0][k][bl];
    __syncthreads();
  }

  // x1 = relu(W1 @ hidden + b1)
  #pragma unroll
  for (int jj = 0; jj < 16; ++jj){
    const int j = q * 16 + jj;
    float acc = b1v[j];
    const float* wr = w1 + j * 64;
    #pragma unroll
    for (int k = 0; k < 64; ++k) acc = fmaf(wr[k], hreg[k], acc);
    hown[jj] = fmaxf(acc, 0.0f);
  }
  #pragma unroll
  for (int jj = 0; jj < 16; ++jj) g_lds[0][q * 16 + jj][bl] = hown[jj];
  __syncthreads();
  float x1[64];
  #pragma unroll
  for (int k = 0; k < 64; ++k) x1[k] = g_lds[0][k][bl];

  // out rows r = q, q+4, q+8 ; dtype-dispatched store
  for (int r = q; r < 9; r += 4){
    float acc = b2v[r];
    const float* wr = w2 + r * 64;
    #pragma unroll
    for (int k = 0; k < 64; ++k) acc = fmaf(wr[k], x1[k], acc);
    if (isbf) ((u16*)out)[(size_t)b * 9 + r] = f2bf(acc);
    else      ((float*)out)[(size_t)b * 9 + r] = acc;
  }
}

extern "C" void kernel_launch(void* const* d_in, const int* in_sizes, int n_in,
                              void* d_out, int out_size, void* d_ws, size_t ws_size,
                              hipStream_t stream){
  char* ws = (char*)d_ws;
  float* WF = (float*)ws;
  size_t off = ((size_t)WF_TOTAL * 4 + 255) & ~(size_t)255;
  u16* xpart = (u16*)(ws + off); off += (size_t)3 * 128 * NB * 2;
  int* flag = (int*)(ws + off);

  PtrTab P;
  for (int i = 0; i < 36; ++i) P.p[i] = d_in[i];

  SegTab S;
  int si = 0;
  for (int t = 0; t < 3; ++t){
    int base = 4 + 8 * t;
    int d = t * TW;
    S.s[si++] = { base + 2, -1,       d + W_WIH,  1536  };  // Wih
    S.s[si++] = { base + 3, -1,       d + W_WHH,  16384 };  // Whh
    S.s[si++] = { base + 4, base + 5, d + W_BSUM, 256   };  // bih + bhh
    S.s[si++] = { base + 6, -1,       d + W_WTS,  4096  };  // WTS
    S.s[si++] = { base + 7, -1,       d + W_BTS,  64    };  // bTS
    S.s[si++] = { base + 0, -1,       d + W_WOS,  448   };  // WOS
    S.s[si++] = { base + 1, -1,       d + W_BOS,  64    };  // bOS
  }
  {
    int O = W_OUT;
    S.s[si++] = { 28, -1, O + WO_WIHO, 32768 };
    S.s[si++] = { 29, -1, O + WO_WHHO, 16384 };
    S.s[si++] = { 30, 31, O + WO_BSUM, 256   };
    S.s[si++] = { 32, -1, O + WO_W1,   4096  };
    S.s[si++] = { 33, -1, O + WO_B1,   64    };
    S.s[si++] = { 34, -1, O + WO_W2,   576   };
    S.s[si++] = { 35, -1, O + WO_B2,   9     };
  }

  const int* hl_ptr = (const int*)d_in[3];

  kdetect<<<dim3(1), 64, 0, stream>>>(d_in[7], flag);
  kweights<<<dim3(28), 256, 0, stream>>>(P, S, WF, flag);
  kmain<<<dim3(NB / 64, 3), 256, 0, stream>>>(d_in[0], d_in[1], hl_ptr, WF, xpart, flag);
  kfinal<<<dim3(NB / 64), 256, 0, stream>>>(WF, xpart, hl_ptr, d_out, flag);
}

// Round 4
// 2506.283 us; speedup vs baseline: 1.9583x; 1.9583x over previous
//
#include <hip/hip_runtime.h>
#include <hip/hip_bf16.h>

#define NB 8192
#define SROW 391

// ---- weight ws layout (floats) ----
#define TW      22848
#define W_WIH   0
#define W_WHH   1536
#define W_BSUM  17920
#define W_WTS   18176
#define W_BTS   22272
#define W_WOS   22336
#define W_BOS   22784
#define W_OUT   68544
#define WO_WIHO 0
#define WO_WHHO 32768
#define WO_BSUM 49152
#define WO_W1   49408
#define WO_B1   53504
#define WO_W2   53568
#define WO_B2   54144
#define WF_TOTAL 122697

typedef unsigned short u16;

__device__ __forceinline__ float bf2f(u16 u){ return __uint_as_float(((unsigned)u) << 16); }
__device__ __forceinline__ u16 f2bf(float f){
  unsigned x = __float_as_uint(f);
  unsigned r = (x + 0x7FFFu + ((x >> 16) & 1u)) >> 16;   // RNE
  return (u16)r;
}
__device__ __forceinline__ bool isnanf32(float f){
  unsigned x = __float_as_uint(f);
  return (x & 0x7FFFFFFFu) > 0x7F800000u;
}
__device__ __forceinline__ float ldin(const void* p, size_t i, bool isbf){
  if (isbf) return bf2f(((const u16*)p)[i]);
  return ((const float*)p)[i];
}
// fast activations: v_exp_f32-based, ~2e-6 abs err, inputs bounded by sigmoid/tanh saturation
__device__ __forceinline__ float sigm(float x){ return __fdividef(1.0f, 1.0f + __expf(-x)); }
__device__ __forceinline__ float tanh_f(float x){ return __fdividef(2.0f, 1.0f + __expf(-2.0f * x)) - 1.0f; }

struct Seg { int src; int src2; int dst; int n; };
struct SegTab { Seg s[28]; };
struct PtrTab { const void* p[36]; };

// ---------- kernel D: detect input dtype from Whh0 bit patterns ----------
__global__ void kdetect(const void* whh0, int* flag){
  if (threadIdx.x == 0 && blockIdx.x == 0){
    const u16* u = (const u16*)whh0;
    int cnt = 0;
    for (int i = 0; i < 128; i += 2){
      int e = (u[i] >> 7) & 0xFF;
      cnt += (e >= 100 && e <= 141) ? 1 : 0;   // bf16 ~64/64 hits; f32 low-halves ~10/64
    }
    *flag = (cnt >= 32) ? 1 : 0;
  }
}

// ---------- kernel W: convert weights -> fp32 into ws ----------
__global__ __launch_bounds__(256) void kweights(PtrTab P, SegTab S, float* __restrict__ WF,
                                                const int* __restrict__ flag){
  const bool isbf = (*flag != 0);
  Seg sg = S.s[blockIdx.x];
  const void* a = P.p[sg.src];
  const void* b = (sg.src2 >= 0) ? P.p[sg.src2] : nullptr;
  for (int i = threadIdx.x; i < sg.n; i += 256){
    float v = ldin(a, i, isbf);
    if (b) v += ldin(b, i, isbf);
    WF[sg.dst + i] = v;
  }
}

// ---------- kernel P: transpose features to [t][step*6+i][b] bf16, count n, compute xOS ----------
__global__ __launch_bounds__(256) void kprep(const void* __restrict__ s,
                                             const void* __restrict__ sh,
                                             const int* __restrict__ hist_len,
                                             const float* __restrict__ WF,
                                             u16* __restrict__ sT,
                                             int* __restrict__ nar,
                                             u16* __restrict__ xpart,
                                             const int* __restrict__ flag){
  const bool isbf = (*flag != 0);
  const int t = blockIdx.y;
  const int b = blockIdx.x * 256 + threadIdx.x;
  const int hl = hist_len[b];

  const void* base; size_t soff; float zf;
  if (t == 0){ base = s;  soff = (size_t)b * SROW; zf = 1.0f; }
  else {
    base = sh; soff = ((size_t)b * 2 + ((t == 1) ? 1 : 0)) * SROW;
    zf = (hl == 2) ? 1.0f : 0.0f;
  }

  int n = 64;
  if (zf != 0.0f){
    n = 0;
    for (int r = 0; r < 64; ++r){
      float f0 = ldin(base, soff + 7 + 6 * r, isbf);
      n += isnanf32(f0) ? 0 : 1;
    }
  }
  nar[t * NB + b] = n;   // valid-prefix length; freeze when step >= n

  for (int r = 0; r < 64; ++r){
    #pragma unroll
    for (int i = 0; i < 6; ++i){
      float f = ldin(base, soff + 7 + 6 * r + i, isbf);
      f = isnanf32(f) ? 0.0f : f * zf;
      sT[((size_t)(t * 384 + r * 6 + i)) * NB + b] = f2bf(f);
    }
  }

  float sOS[7];
  #pragma unroll
  for (int i = 0; i < 7; ++i) sOS[i] = ldin(base, soff + i, isbf) * zf;
  const float* wos = WF + t * TW + W_WOS;
  const float* bos = WF + t * TW + W_BOS;
  for (int j = 0; j < 64; ++j){
    float acc = bos[j];
    #pragma unroll
    for (int i = 0; i < 7; ++i) acc = fmaf(wos[j * 7 + i], sOS[i], acc);
    xpart[((size_t)(t * 128 + j)) * NB + b] = f2bf(fmaxf(acc, 0.0f));
  }
}

// ---------- kernel M: inner LSTM. wave q owns units [q*16,+16): all 4 gates, scalar weights ----------
__global__ __launch_bounds__(256) void kmain(const int* __restrict__ nar,
                                             const float* __restrict__ WF,
                                             const u16* __restrict__ sT,
                                             u16* __restrict__ xpart){
  __shared__ float h_lds[64][64];   // 16 KB: h broadcast only
  const int t  = blockIdx.y;
  const int bl = threadIdx.x & 63;
  const int q  = __builtin_amdgcn_readfirstlane((int)(threadIdx.x >> 6));  // wave-uniform -> SGPR weight addressing
  const int b  = blockIdx.x * 64 + bl;
  const int n  = nar[t * NB + b];

  const float* Wt   = WF + t * TW;
  const float* wih  = Wt + W_WIH;
  const float* whh  = Wt + W_WHH;
  const float* bsum = Wt + W_BSUM;
  const float* wts  = Wt + W_WTS;
  const float* bts  = Wt + W_BTS;
  const u16* sTb = sT + (size_t)(t * 384) * NB + b;

  float hreg[64], hown[16], creg[16];
  #pragma unroll
  for (int k = 0; k < 64; ++k) hreg[k] = 0.0f;
  #pragma unroll
  for (int k = 0; k < 16; ++k){ hown[k] = 0.0f; creg[k] = 0.0f; }

  for (int step = 0; step < 64; ++step){
    float sv[6];
    #pragma unroll
    for (int i = 0; i < 6; ++i) sv[i] = bf2f(sTb[(size_t)(step * 6 + i) * NB]);
    const bool rowvalid = (step < n);

    for (int jj = 0; jj < 16; ++jj){
      const int u = q * 16 + jj;           // wave-uniform row index
      float ai = bsum[u];
      float af = bsum[64 + u];
      float ag = bsum[128 + u];
      float ao = bsum[192 + u];
      const float* wiI = wih + u * 6;
      const float* wiF = wih + (64 + u) * 6;
      const float* wiG = wih + (128 + u) * 6;
      const float* wiO = wih + (192 + u) * 6;
      #pragma unroll
      for (int i = 0; i < 6; ++i){
        float x = sv[i];
        ai = fmaf(wiI[i], x, ai); af = fmaf(wiF[i], x, af);
        ag = fmaf(wiG[i], x, ag); ao = fmaf(wiO[i], x, ao);
      }
      const float* whI = whh + u * 64;
      const float* whF = whh + (64 + u) * 64;
      const float* whG = whh + (128 + u) * 64;
      const float* whO = whh + (192 + u) * 64;
      #pragma unroll
      for (int k = 0; k < 64; ++k){        // 4 independent chains -> ILP 4
        float hk = hreg[k];
        ai = fmaf(whI[k], hk, ai); af = fmaf(whF[k], hk, af);
        ag = fmaf(whG[k], hk, ag); ao = fmaf(whO[k], hk, ao);
      }
      float c  = sigm(af) * creg[jj] + sigm(ai) * tanh_f(ag);
      float hn = sigm(ao) * tanh_f(c);
      creg[jj] = rowvalid ? c  : creg[jj];
      hown[jj] = rowvalid ? hn : hown[jj];
    }

    __syncthreads();   // all hreg reads of previous h done before overwrite
    #pragma unroll
    for (int jj = 0; jj < 16; ++jj) h_lds[q * 16 + jj][bl] = hown[jj];
    __syncthreads();
    #pragma unroll
    for (int k = 0; k < 64; ++k) hreg[k] = h_lds[k][bl];
  }

  // xTS = relu(WTS @ h + bTS) for this wave's 16 units
  #pragma unroll
  for (int jj = 0; jj < 16; ++jj){
    const int u = q * 16 + jj;
    float a0 = 0.0f, a1 = 0.0f, a2 = 0.0f, a3 = 0.0f;
    const float* wr = wts + u * 64;
    #pragma unroll
    for (int k = 0; k < 64; k += 4){
      a0 = fmaf(wr[k],     hreg[k],     a0);
      a1 = fmaf(wr[k + 1], hreg[k + 1], a1);
      a2 = fmaf(wr[k + 2], hreg[k + 2], a2);
      a3 = fmaf(wr[k + 3], hreg[k + 3], a3);
    }
    float acc = bts[u] + (a0 + a1) + (a2 + a3);
    xpart[((size_t)(t * 128 + 64 + u)) * NB + b] = f2bf(fmaxf(acc, 0.0f));
  }
}

// ---------- kernel F: outer LSTM (3 steps, Wiho@x inline) + MLP ----------
__global__ __launch_bounds__(256) void kfinal(const float* __restrict__ WF,
                                              const u16* __restrict__ xpart,
                                              const int* __restrict__ hist_len,
                                              void* __restrict__ out,
                                              const int* __restrict__ flag){
  __shared__ float h_lds[64][64];   // 16 KB
  const bool isbf = (*flag != 0);
  const int bl = threadIdx.x & 63;
  const int q  = __builtin_amdgcn_readfirstlane((int)(threadIdx.x >> 6));
  const int b  = blockIdx.x * 64 + bl;
  const int hl = hist_len[b];

  const float* WO    = WF + W_OUT;
  const float* wiho  = WO + WO_WIHO;
  const float* whho  = WO + WO_WHHO;
  const float* bsumo = WO + WO_BSUM;
  const float* w1    = WO + WO_W1;
  const float* b1v   = WO + WO_B1;
  const float* w2    = WO + WO_W2;
  const float* b2v   = WO + WO_B2;

  float hreg[64], hown[16], creg[16];
  #pragma unroll
  for (int k = 0; k < 64; ++k) hreg[k] = 0.0f;
  #pragma unroll
  for (int k = 0; k < 16; ++k){ hown[k] = 0.0f; creg[k] = 0.0f; }

  for (int p = 0; p < 3; ++p){
    const int tt = 2 - ((p - hl + 2) % 3);
    const u16* xb = xpart + (size_t)(tt * 128) * NB + b;
    const bool rowvalid = (p <= hl);

    float xv[128];
    #pragma unroll
    for (int i = 0; i < 128; ++i) xv[i] = bf2f(xb[(size_t)i * NB]);

    for (int jj = 0; jj < 16; ++jj){
      const int u = q * 16 + jj;
      float ai = bsumo[u];
      float af = bsumo[64 + u];
      float ag = bsumo[128 + u];
      float ao = bsumo[192 + u];
      const float* iI = wiho + u * 128;
      const float* iF = wiho + (64 + u) * 128;
      const float* iG = wiho + (128 + u) * 128;
      const float* iO = wiho + (192 + u) * 128;
      #pragma unroll
      for (int i = 0; i < 128; ++i){
        float x = xv[i];
        ai = fmaf(iI[i], x, ai); af = fmaf(iF[i], x, af);
        ag = fmaf(iG[i], x, ag); ao = fmaf(iO[i], x, ao);
      }
      const float* hI = whho + u * 64;
      const float* hF = whho + (64 + u) * 64;
      const float* hG = whho + (128 + u) * 64;
      const float* hO = whho + (192 + u) * 64;
      #pragma unroll
      for (int k = 0; k < 64; ++k){
        float hk = hreg[k];
        ai = fmaf(hI[k], hk, ai); af = fmaf(hF[k], hk, af);
        ag = fmaf(hG[k], hk, ag); ao = fmaf(hO[k], hk, ao);
      }
      float c  = sigm(af) * creg[jj] + sigm(ai) * tanh_f(ag);
      float hn = sigm(ao) * tanh_f(c);
      creg[jj] = rowvalid ? c  : creg[jj];
      hown[jj] = rowvalid ? hn : hown[jj];
    }

    __syncthreads();
    #pragma unroll
    for (int jj = 0; jj < 16; ++jj) h_lds[q * 16 + jj][bl] = hown[jj];
    __syncthreads();
    #pragma unroll
    for (int k = 0; k < 64; ++k) hreg[k] = h_lds[k][bl];
  }

  __syncthreads();   // reuse h_lds for x1 exchange

  // x1 = relu(W1 @ hidden + b1)
  #pragma unroll
  for (int jj = 0; jj < 16; ++jj){
    const int u = q * 16 + jj;
    float a0 = 0.0f, a1 = 0.0f, a2 = 0.0f, a3 = 0.0f;
    const float* wr = w1 + u * 64;
    #pragma unroll
    for (int k = 0; k < 64; k += 4){
      a0 = fmaf(wr[k],     hreg[k],     a0);
      a1 = fmaf(wr[k + 1], hreg[k + 1], a1);
      a2 = fmaf(wr[k + 2], hreg[k + 2], a2);
      a3 = fmaf(wr[k + 3], hreg[k + 3], a3);
    }
    h_lds[u][bl] = fmaxf(b1v[u] + (a0 + a1) + (a2 + a3), 0.0f);
  }
  __syncthreads();
  float x1[64];
  #pragma unroll
  for (int k = 0; k < 64; ++k) x1[k] = h_lds[k][bl];

  for (int r = q; r < 9; r += 4){
    float acc = b2v[r];
    const float* wr = w2 + r * 64;
    #pragma unroll
    for (int k = 0; k < 64; ++k) acc = fmaf(wr[k], x1[k], acc);
    if (isbf) ((u16*)out)[(size_t)b * 9 + r] = f2bf(acc);
    else      ((float*)out)[(size_t)b * 9 + r] = acc;
  }
}

extern "C" void kernel_launch(void* const* d_in, const int* in_sizes, int n_in,
                              void* d_out, int out_size, void* d_ws, size_t ws_size,
                              hipStream_t stream){
  char* ws = (char*)d_ws;
  float* WF = (float*)ws;
  size_t off = ((size_t)WF_TOTAL * 4 + 255) & ~(size_t)255;
  u16* sT = (u16*)(ws + off);     off += (size_t)3 * 384 * NB * 2;
  u16* xpart = (u16*)(ws + off);  off += (size_t)3 * 128 * NB * 2;
  int* nar = (int*)(ws + off);    off += (size_t)3 * NB * 4;
  int* flag = (int*)(ws + off);

  PtrTab P;
  for (int i = 0; i < 36; ++i) P.p[i] = d_in[i];

  SegTab S;
  int si = 0;
  for (int t = 0; t < 3; ++t){
    int base = 4 + 8 * t;
    int d = t * TW;
    S.s[si++] = { base + 2, -1,       d + W_WIH,  1536  };
    S.s[si++] = { base + 3, -1,       d + W_WHH,  16384 };
    S.s[si++] = { base + 4, base + 5, d + W_BSUM, 256   };
    S.s[si++] = { base + 6, -1,       d + W_WTS,  4096  };
    S.s[si++] = { base + 7, -1,       d + W_BTS,  64    };
    S.s[si++] = { base + 0, -1,       d + W_WOS,  448   };
    S.s[si++] = { base + 1, -1,       d + W_BOS,  64    };
  }
  {
    int O = W_OUT;
    S.s[si++] = { 28, -1, O + WO_WIHO, 32768 };
    S.s[si++] = { 29, -1, O + WO_WHHO, 16384 };
    S.s[si++] = { 30, 31, O + WO_BSUM, 256   };
    S.s[si++] = { 32, -1, O + WO_W1,   4096  };
    S.s[si++] = { 33, -1, O + WO_B1,   64    };
    S.s[si++] = { 34, -1, O + WO_W2,   576   };
    S.s[si++] = { 35, -1, O + WO_B2,   9     };
  }

  const int* hl_ptr = (const int*)d_in[3];

  kdetect<<<dim3(1), 64, 0, stream>>>(d_in[7], flag);
  kweights<<<dim3(28), 256, 0, stream>>>(P, S, WF, flag);
  kprep<<<dim3(NB / 256, 3), 256, 0, stream>>>(d_in[0], d_in[1], hl_ptr, WF, sT, nar, xpart, flag);
  kmain<<<dim3(NB / 64, 3), 256, 0, stream>>>(nar, WF, sT, xpart);
  kfinal<<<dim3(NB / 64), 256, 0, stream>>>(WF, xpart, hl_ptr, d_out, flag);
}

// Round 5
// 736.582 us; speedup vs baseline: 6.6633x; 3.4026x over previous
//
#include <hip/hip_runtime.h>
#include <hip/hip_bf16.h>

#define NB 8192
#define SROW 391

// ---- weight ws layout (floats) ----
#define TW      22848
#define W_WIH   0
#define W_WHH   1536
#define W_BSUM  17920
#define W_WTS   18176
#define W_BTS   22272
#define W_WOS   22336
#define W_BOS   22784
#define W_OUT   68544
#define WO_WIHO 0
#define WO_WHHO 32768
#define WO_BSUM 49152
#define WO_W1   49408
#define WO_B1   53504
#define WO_W2   53568
#define WO_B2   54144
#define WF_TOTAL 122697

typedef unsigned short u16;
typedef __attribute__((ext_vector_type(8))) short short8;
typedef __attribute__((ext_vector_type(4))) float float4v;

#define MFMA16(a, b, c) __builtin_amdgcn_mfma_f32_16x16x32_bf16((a), (b), (c), 0, 0, 0)

__device__ __forceinline__ float bf2f(u16 u){ return __uint_as_float(((unsigned)u) << 16); }
__device__ __forceinline__ u16 f2bf(float f){
  unsigned x = __float_as_uint(f);
  unsigned r = (x + 0x7FFFu + ((x >> 16) & 1u)) >> 16;   // RNE
  return (u16)r;
}
__device__ __forceinline__ bool isnanf32(float f){
  unsigned x = __float_as_uint(f);
  return (x & 0x7FFFFFFFu) > 0x7F800000u;
}
__device__ __forceinline__ float ldin(const void* p, size_t i, bool isbf){
  if (isbf) return bf2f(((const u16*)p)[i]);
  return ((const float*)p)[i];
}
__device__ __forceinline__ float sigm(float x){ return __fdividef(1.0f, 1.0f + __expf(-x)); }
__device__ __forceinline__ float tanh_f(float x){ return __fdividef(2.0f, 1.0f + __expf(-2.0f * x)) - 1.0f; }

struct Seg { int src; int src2; int dst; int n; };
struct SegTab { Seg s[28]; };
struct PtrTab { const void* p[36]; };

// ---------- kernel D: detect input dtype from Whh0 bit patterns ----------
__global__ void kdetect(const void* whh0, int* flag){
  if (threadIdx.x == 0 && blockIdx.x == 0){
    const u16* u = (const u16*)whh0;
    int cnt = 0;
    for (int i = 0; i < 128; i += 2){
      int e = (u[i] >> 7) & 0xFF;
      cnt += (e >= 100 && e <= 141) ? 1 : 0;
    }
    *flag = (cnt >= 32) ? 1 : 0;
  }
}

// ---------- kernel W: convert weights -> fp32 into ws ----------
__global__ __launch_bounds__(256) void kweights(PtrTab P, SegTab S, float* __restrict__ WF,
                                                const int* __restrict__ flag){
  const bool isbf = (*flag != 0);
  Seg sg = S.s[blockIdx.x];
  const void* a = P.p[sg.src];
  const void* b = (sg.src2 >= 0) ? P.p[sg.src2] : nullptr;
  for (int i = threadIdx.x; i < sg.n; i += 256){
    float v = ldin(a, i, isbf);
    if (b) v += ldin(b, i, isbf);
    WF[sg.dst + i] = v;
  }
}

// ---------- kernel P: write sTx[t][step][b][8] bf16, nar, xOS -> xpartT[t][b][0..63] ----------
__global__ __launch_bounds__(256) void kprep(const void* __restrict__ s,
                                             const void* __restrict__ sh,
                                             const int* __restrict__ hist_len,
                                             const float* __restrict__ WF,
                                             u16* __restrict__ sTx,
                                             int* __restrict__ nar,
                                             u16* __restrict__ xpartT,
                                             const int* __restrict__ flag){
  const bool isbf = (*flag != 0);
  const int t = blockIdx.y;
  const int b = blockIdx.x * 256 + threadIdx.x;
  const int hl = hist_len[b];

  const void* base; size_t soff; float zf;
  if (t == 0){ base = s;  soff = (size_t)b * SROW; zf = 1.0f; }
  else {
    base = sh; soff = ((size_t)b * 2 + ((t == 1) ? 1 : 0)) * SROW;
    zf = (hl == 2) ? 1.0f : 0.0f;
  }

  int n = 64;
  if (zf != 0.0f){
    n = 0;
    for (int r = 0; r < 64; ++r){
      float f0 = ldin(base, soff + 7 + 6 * r, isbf);
      n += isnanf32(f0) ? 0 : 1;
    }
  }
  nar[t * NB + b] = n;

  for (int r = 0; r < 64; ++r){
    u16 v[6];
    #pragma unroll
    for (int i = 0; i < 6; ++i){
      float f = ldin(base, soff + 7 + 6 * r + i, isbf);
      f = isnanf32(f) ? 0.0f : f * zf;
      v[i] = f2bf(f);
    }
    uint4 w;
    w.x = (uint)v[0] | ((uint)v[1] << 16);
    w.y = (uint)v[2] | ((uint)v[3] << 16);
    w.z = (uint)v[4] | ((uint)v[5] << 16);
    w.w = 0u;
    *(uint4*)&sTx[(((size_t)(t * 64 + r)) * NB + b) * 8] = w;
  }

  float sOS[7];
  #pragma unroll
  for (int i = 0; i < 7; ++i) sOS[i] = ldin(base, soff + i, isbf) * zf;
  const float* wos = WF + t * TW + W_WOS;
  const float* bos = WF + t * TW + W_BOS;
  u16* xo = xpartT + ((size_t)(t * NB + b)) * 128;
  for (int j = 0; j < 64; ++j){
    float acc = bos[j];
    #pragma unroll
    for (int i = 0; i < 7; ++i) acc = fmaf(wos[j * 7 + i], sOS[i], acc);
    xo[j] = f2bf(fmaxf(acc, 0.0f));
  }
}

// ---------- kernel M: inner LSTM via MFMA. 4 waves, wave q = units [q*16,+16) across 4 gates ----------
__global__ __launch_bounds__(256) void kmainM(const int* __restrict__ nar,
                                              const float* __restrict__ WF,
                                              const u16* __restrict__ sTx,
                                              u16* __restrict__ xpartT){
  __shared__ u16 hHi[64 * 72];   // [b][unit] bf16, row stride 72 (pad 8) -> conflict-free-ish b128 reads
  __shared__ u16 hLo[64 * 72];
  const int t    = blockIdx.y;
  const int b0   = blockIdx.x * 64;
  const int lane = threadIdx.x & 63;
  const int q    = __builtin_amdgcn_readfirstlane((int)(threadIdx.x >> 6));
  const int nlo  = lane & 15;
  const int quad = lane >> 4;

  for (int i = threadIdx.x; i < 64 * 72; i += 256){ hHi[i] = 0; hLo[i] = 0; }

  const float* Wt = WF + t * TW;
  short8 aW[4][2], aX[4];
  float4v binit[4];
  #pragma unroll
  for (int g = 0; g < 4; ++g){
    const int mrow = g * 64 + q * 16 + nlo;         // A-frag: m = lane&15
    const float* wr = Wt + W_WHH + mrow * 64;
    #pragma unroll
    for (int f = 0; f < 2; ++f){
      const int k0 = f * 32 + quad * 8;             // A-frag: k = quad*8 + j (+32 per frag)
      short8 a;
      #pragma unroll
      for (int j = 0; j < 8; ++j) a[j] = (short)f2bf(wr[k0 + j]);
      aW[g][f] = a;
    }
    const float* wi = Wt + W_WIH + mrow * 6;
    short8 ax = {0, 0, 0, 0, 0, 0, 0, 0};
    if (quad == 0){
      #pragma unroll
      for (int j = 0; j < 6; ++j) ax[j] = (short)f2bf(wi[j]);
    }
    aX[g] = ax;
    binit[g] = *(const float4v*)(Wt + W_BSUM + g * 64 + q * 16 + quad * 4);
  }
  int n4[4];
  #pragma unroll
  for (int nt = 0; nt < 4; ++nt) n4[nt] = nar[t * NB + b0 + nt * 16 + nlo];

  float c_st[4][4], h_st[4][4];
  #pragma unroll
  for (int nt = 0; nt < 4; ++nt)
    #pragma unroll
    for (int r = 0; r < 4; ++r){ c_st[nt][r] = 0.0f; h_st[nt][r] = 0.0f; }

  const u16* sB = sTx + ((size_t)(t * 64) * NB + b0) * 8;
  __syncthreads();

  for (int step = 0; step < 64; ++step){
    float4v acc[4][4];
    #pragma unroll
    for (int nt = 0; nt < 4; ++nt){
      short8 xf = {0, 0, 0, 0, 0, 0, 0, 0};
      if (lane < 16) xf = *(const short8*)(sB + ((size_t)step * NB + nt * 16 + lane) * 8);
      const int hb = (nt * 16 + nlo) * 72 + quad * 8;   // B-frag: n = lane&15, k = quad*8+j
      short8 h0 = *(const short8*)&hHi[hb];
      short8 h1 = *(const short8*)&hHi[hb + 32];
      short8 l0 = *(const short8*)&hLo[hb];
      short8 l1 = *(const short8*)&hLo[hb + 32];
      #pragma unroll
      for (int g = 0; g < 4; ++g){
        float4v a = binit[g];
        a = MFMA16(aX[g], xf, a);
        a = MFMA16(aW[g][0], h0, a);
        a = MFMA16(aW[g][1], h1, a);
        a = MFMA16(aW[g][0], l0, a);
        a = MFMA16(aW[g][1], l1, a);
        acc[g][nt] = a;
      }
    }
    __syncthreads();   // all LDS reads done before h overwrite
    #pragma unroll
    for (int nt = 0; nt < 4; ++nt){
      const bool v = (step < n4[nt]);
      u16 hb4[4], lb4[4];
      #pragma unroll
      for (int r = 0; r < 4; ++r){
        float gi = acc[0][nt][r], gf = acc[1][nt][r], gg = acc[2][nt][r], go = acc[3][nt][r];
        float cn = sigm(gf) * c_st[nt][r] + sigm(gi) * tanh_f(gg);
        float hn = sigm(go) * tanh_f(cn);
        c_st[nt][r] = v ? cn : c_st[nt][r];
        h_st[nt][r] = v ? hn : h_st[nt][r];
        u16 hi = f2bf(h_st[nt][r]);
        float lo = h_st[nt][r] - bf2f(hi);
        hb4[r] = hi; lb4[r] = f2bf(lo);
      }
      const int off = (nt * 16 + nlo) * 72 + q * 16 + quad * 4;   // C-layout: row=quad*4+r, col=lane&15
      uint2 hw, lw;
      hw.x = (uint)hb4[0] | ((uint)hb4[1] << 16);
      hw.y = (uint)hb4[2] | ((uint)hb4[3] << 16);
      lw.x = (uint)lb4[0] | ((uint)lb4[1] << 16);
      lw.y = (uint)lb4[2] | ((uint)lb4[3] << 16);
      *(uint2*)&hHi[off] = hw;
      *(uint2*)&hLo[off] = lw;
    }
    __syncthreads();
  }

  // xTS = relu(WTS @ h + bTS) via MFMA; wave q -> output units [q*16,+16)
  short8 aT[2];
  #pragma unroll
  for (int f = 0; f < 2; ++f){
    const float* wr = Wt + W_WTS + (q * 16 + nlo) * 64 + f * 32 + quad * 8;
    short8 a;
    #pragma unroll
    for (int j = 0; j < 8; ++j) a[j] = (short)f2bf(wr[j]);
    aT[f] = a;
  }
  float4v btsv = *(const float4v*)(Wt + W_BTS + q * 16 + quad * 4);
  #pragma unroll
  for (int nt = 0; nt < 4; ++nt){
    const int hb = (nt * 16 + nlo) * 72 + quad * 8;
    short8 h0 = *(const short8*)&hHi[hb];
    short8 h1 = *(const short8*)&hHi[hb + 32];
    short8 l0 = *(const short8*)&hLo[hb];
    short8 l1 = *(const short8*)&hLo[hb + 32];
    float4v a = btsv;
    a = MFMA16(aT[0], h0, a);
    a = MFMA16(aT[1], h1, a);
    a = MFMA16(aT[0], l0, a);
    a = MFMA16(aT[1], l1, a);
    u16 o4[4];
    #pragma unroll
    for (int r = 0; r < 4; ++r) o4[r] = f2bf(fmaxf(a[r], 0.0f));
    size_t idx = ((size_t)(t * NB + b0 + nt * 16 + nlo)) * 128 + 64 + q * 16 + quad * 4;
    uint2 w;
    w.x = (uint)o4[0] | ((uint)o4[1] << 16);
    w.y = (uint)o4[2] | ((uint)o4[3] << 16);
    *(uint2*)&xpartT[idx] = w;
  }
}

// ---------- kernel F: outer LSTM via MFMA (3 steps) + MLP ----------
__global__ __launch_bounds__(256) void kfinalM(const float* __restrict__ WF,
                                               const u16* __restrict__ xpartT,
                                               const int* __restrict__ hist_len,
                                               void* __restrict__ out,
                                               const int* __restrict__ flag){
  __shared__ u16 hHi[64 * 72];
  __shared__ u16 hLo[64 * 72];
  __shared__ float x1T[64 * 68];
  const bool isbf = (*flag != 0);
  const int b0   = blockIdx.x * 64;
  const int lane = threadIdx.x & 63;
  const int q    = __builtin_amdgcn_readfirstlane((int)(threadIdx.x >> 6));
  const int nlo  = lane & 15;
  const int quad = lane >> 4;

  for (int i = threadIdx.x; i < 64 * 72; i += 256){ hHi[i] = 0; hLo[i] = 0; }

  const float* WO = WF + W_OUT;
  int hl4[4];
  #pragma unroll
  for (int nt = 0; nt < 4; ++nt) hl4[nt] = hist_len[b0 + nt * 16 + nlo];

  float c_st[4][4], h_st[4][4];
  #pragma unroll
  for (int nt = 0; nt < 4; ++nt)
    #pragma unroll
    for (int r = 0; r < 4; ++r){ c_st[nt][r] = 0.0f; h_st[nt][r] = 0.0f; }
  __syncthreads();

  for (int p = 0; p < 3; ++p){
    float4v acc[4][4];
    #pragma unroll
    for (int g = 0; g < 4; ++g){
      const int mrow = g * 64 + q * 16 + nlo;
      short8 aI[4], aH[2];
      #pragma unroll
      for (int f = 0; f < 4; ++f){
        const float* w = WO + WO_WIHO + mrow * 128 + f * 32 + quad * 8;
        short8 a;
        #pragma unroll
        for (int j = 0; j < 8; ++j) a[j] = (short)f2bf(w[j]);
        aI[f] = a;
      }
      #pragma unroll
      for (int f = 0; f < 2; ++f){
        const float* w = WO + WO_WHHO + mrow * 64 + f * 32 + quad * 8;
        short8 a;
        #pragma unroll
        for (int j = 0; j < 8; ++j) a[j] = (short)f2bf(w[j]);
        aH[f] = a;
      }
      float4v bi = *(const float4v*)(WO + WO_BSUM + g * 64 + q * 16 + quad * 4);
      #pragma unroll
      for (int nt = 0; nt < 4; ++nt){
        const int bb = b0 + nt * 16 + nlo;
        const int tt = 2 - ((p - hl4[nt] + 2) % 3);
        const u16* xb = xpartT + ((size_t)(tt * NB + bb)) * 128;
        float4v a = bi;
        #pragma unroll
        for (int f = 0; f < 4; ++f){
          short8 xf = *(const short8*)(xb + f * 32 + quad * 8);
          a = MFMA16(aI[f], xf, a);
        }
        const int hb = (nt * 16 + nlo) * 72 + quad * 8;
        a = MFMA16(aH[0], *(const short8*)&hHi[hb], a);
        a = MFMA16(aH[1], *(const short8*)&hHi[hb + 32], a);
        a = MFMA16(aH[0], *(const short8*)&hLo[hb], a);
        a = MFMA16(aH[1], *(const short8*)&hLo[hb + 32], a);
        acc[g][nt] = a;
      }
    }
    __syncthreads();
    #pragma unroll
    for (int nt = 0; nt < 4; ++nt){
      const bool v = (p <= hl4[nt]);
      u16 hb4[4], lb4[4];
      #pragma unroll
      for (int r = 0; r < 4; ++r){
        float gi = acc[0][nt][r], gf = acc[1][nt][r], gg = acc[2][nt][r], go = acc[3][nt][r];
        float cn = sigm(gf) * c_st[nt][r] + sigm(gi) * tanh_f(gg);
        float hn = sigm(go) * tanh_f(cn);
        c_st[nt][r] = v ? cn : c_st[nt][r];
        h_st[nt][r] = v ? hn : h_st[nt][r];
        u16 hi = f2bf(h_st[nt][r]);
        float lo = h_st[nt][r] - bf2f(hi);
        hb4[r] = hi; lb4[r] = f2bf(lo);
      }
      const int off = (nt * 16 + nlo) * 72 + q * 16 + quad * 4;
      uint2 hw, lw;
      hw.x = (uint)hb4[0] | ((uint)hb4[1] << 16);
      hw.y = (uint)hb4[2] | ((uint)hb4[3] << 16);
      lw.x = (uint)lb4[0] | ((uint)lb4[1] << 16);
      lw.y = (uint)lb4[2] | ((uint)lb4[3] << 16);
      *(uint2*)&hHi[off] = hw;
      *(uint2*)&hLo[off] = lw;
    }
    __syncthreads();
  }

  // x1 = relu(W1 @ hidden + b1) via MFMA
  short8 a1[2];
  #pragma unroll
  for (int f = 0; f < 2; ++f){
    const float* w = WO + WO_W1 + (q * 16 + nlo) * 64 + f * 32 + quad * 8;
    short8 a;
    #pragma unroll
    for (int j = 0; j < 8; ++j) a[j] = (short)f2bf(w[j]);
    a1[f] = a;
  }
  float4v b1v = *(const float4v*)(WO + WO_B1 + q * 16 + quad * 4);
  #pragma unroll
  for (int nt = 0; nt < 4; ++nt){
    const int hb = (nt * 16 + nlo) * 72 + quad * 8;
    float4v a = b1v;
    a = MFMA16(a1[0], *(const short8*)&hHi[hb], a);
    a = MFMA16(a1[1], *(const short8*)&hHi[hb + 32], a);
    a = MFMA16(a1[0], *(const short8*)&hLo[hb], a);
    a = MFMA16(a1[1], *(const short8*)&hLo[hb + 32], a);
    float4v rv;
    #pragma unroll
    for (int r = 0; r < 4; ++r) rv[r] = fmaxf(a[r], 0.0f);
    *(float4v*)&x1T[(nt * 16 + nlo) * 68 + q * 16 + quad * 4] = rv;
  }
  __syncthreads();

  // out = W2 @ x1 + b2 ; threads: bloc = tid>>2 (0..63), rows r = (tid&3), +4, +8
  const int bloc = threadIdx.x >> 2;
  const int r0 = threadIdx.x & 3;
  const float* w2 = WO + WO_W2;
  const float* b2 = WO + WO_B2;
  for (int r = r0; r < 9; r += 4){
    float acc = b2[r];
    const float* wr = w2 + r * 64;
    #pragma unroll
    for (int k = 0; k < 64; ++k) acc = fmaf(wr[k], x1T[bloc * 68 + k], acc);
    if (isbf) ((u16*)out)[(size_t)(b0 + bloc) * 9 + r] = f2bf(acc);
    else      ((float*)out)[(size_t)(b0 + bloc) * 9 + r] = acc;
  }
}

extern "C" void kernel_launch(void* const* d_in, const int* in_sizes, int n_in,
                              void* d_out, int out_size, void* d_ws, size_t ws_size,
                              hipStream_t stream){
  char* ws = (char*)d_ws;
  float* WF = (float*)ws;
  size_t off = ((size_t)WF_TOTAL * 4 + 255) & ~(size_t)255;
  u16* sTx = (u16*)(ws + off);    off += (size_t)3 * 64 * NB * 8 * 2;   // 25.2 MB
  u16* xpartT = (u16*)(ws + off); off += (size_t)3 * NB * 128 * 2;      // 6.3 MB
  int* nar = (int*)(ws + off);    off += (size_t)3 * NB * 4;
  int* flag = (int*)(ws + off);

  PtrTab P;
  for (int i = 0; i < 36; ++i) P.p[i] = d_in[i];

  SegTab S;
  int si = 0;
  for (int t = 0; t < 3; ++t){
    int base = 4 + 8 * t;
    int d = t * TW;
    S.s[si++] = { base + 2, -1,       d + W_WIH,  1536  };
    S.s[si++] = { base + 3, -1,       d + W_WHH,  16384 };
    S.s[si++] = { base + 4, base + 5, d + W_BSUM, 256   };
    S.s[si++] = { base + 6, -1,       d + W_WTS,  4096  };
    S.s[si++] = { base + 7, -1,       d + W_BTS,  64    };
    S.s[si++] = { base + 0, -1,       d + W_WOS,  448   };
    S.s[si++] = { base + 1, -1,       d + W_BOS,  64    };
  }
  {
    int O = W_OUT;
    S.s[si++] = { 28, -1, O + WO_WIHO, 32768 };
    S.s[si++] = { 29, -1, O + WO_WHHO, 16384 };
    S.s[si++] = { 30, 31, O + WO_BSUM, 256   };
    S.s[si++] = { 32, -1, O + WO_W1,   4096  };
    S.s[si++] = { 33, -1, O + WO_B1,   64    };
    S.s[si++] = { 34, -1, O + WO_W2,   576   };
    S.s[si++] = { 35, -1, O + WO_B2,   9     };
  }

  const int* hl_ptr = (const int*)d_in[3];

  kdetect<<<dim3(1), 64, 0, stream>>>(d_in[7], flag);
  kweights<<<dim3(28), 256, 0, stream>>>(P, S, WF, flag);
  kprep<<<dim3(NB / 256, 3), 256, 0, stream>>>(d_in[0], d_in[1], hl_ptr, WF, sTx, nar, xpartT, flag);
  kmainM<<<dim3(NB / 64, 3), 256, 0, stream>>>(nar, WF, sTx, xpartT);
  kfinalM<<<dim3(NB / 64), 256, 0, stream>>>(WF, xpartT, hl_ptr, d_out, flag);
}

// Round 6
// 685.497 us; speedup vs baseline: 7.1598x; 1.0745x over previous
//
#include <hip/hip_runtime.h>
#include <hip/hip_bf16.h>

#define NB 8192
#define SROW 391

// ---- weight ws layout (floats) ----
#define TW      22848
#define W_WIH   0
#define W_WHH   1536
#define W_BSUM  17920
#define W_WTS   18176
#define W_BTS   22272
#define W_WOS   22336
#define W_BOS   22784
#define W_OUT   68544
#define WO_WIHO 0
#define WO_WHHO 32768
#define WO_BSUM 49152
#define WO_W1   49408
#define WO_B1   53504
#define WO_W2   53568
#define WO_B2   54144
#define WF_TOTAL 122697

typedef unsigned short u16;
typedef __attribute__((ext_vector_type(8))) short short8;
typedef __attribute__((ext_vector_type(4))) float float4v;

#define MFMA16(a, b, c) __builtin_amdgcn_mfma_f32_16x16x32_bf16((a), (b), (c), 0, 0, 0)

__device__ __forceinline__ float bf2f(u16 u){ return __uint_as_float(((unsigned)u) << 16); }
__device__ __forceinline__ u16 f2bf(float f){
  unsigned x = __float_as_uint(f);
  unsigned r = (x + 0x7FFFu + ((x >> 16) & 1u)) >> 16;   // RNE
  return (u16)r;
}
__device__ __forceinline__ bool isnanf32(float f){
  unsigned x = __float_as_uint(f);
  return (x & 0x7FFFFFFFu) > 0x7F800000u;
}
__device__ __forceinline__ float ldin(const void* p, size_t i, bool isbf){
  if (isbf) return bf2f(((const u16*)p)[i]);
  return ((const float*)p)[i];
}
__device__ __forceinline__ float sigm(float x){ return __fdividef(1.0f, 1.0f + __expf(-x)); }
__device__ __forceinline__ float tanh_f(float x){ return __fdividef(2.0f, 1.0f + __expf(-2.0f * x)) - 1.0f; }

struct Seg { int src; int src2; int dst; int n; };
struct SegTab { Seg s[28]; };
struct PtrTab { const void* p[36]; };

// ---------- kernel D: detect input dtype from Whh0 bit patterns ----------
__global__ void kdetect(const void* whh0, int* flag){
  if (threadIdx.x == 0 && blockIdx.x == 0){
    const u16* u = (const u16*)whh0;
    int cnt = 0;
    for (int i = 0; i < 128; i += 2){
      int e = (u[i] >> 7) & 0xFF;
      cnt += (e >= 100 && e <= 141) ? 1 : 0;
    }
    *flag = (cnt >= 32) ? 1 : 0;
  }
}

// ---------- kernel W: convert weights -> fp32 into ws ----------
__global__ __launch_bounds__(256) void kweights(PtrTab P, SegTab S, float* __restrict__ WF,
                                                const int* __restrict__ flag){
  const bool isbf = (*flag != 0);
  Seg sg = S.s[blockIdx.x];
  const void* a = P.p[sg.src];
  const void* b = (sg.src2 >= 0) ? P.p[sg.src2] : nullptr;
  for (int i = threadIdx.x; i < sg.n; i += 256){
    float v = ldin(a, i, isbf);
    if (b) v += ldin(b, i, isbf);
    WF[sg.dst + i] = v;
  }
}

// ---------- kernel P: sTx[t][step][b][8] bf16 (only nonzero seqs), nar, xOS ----------
__global__ __launch_bounds__(256) void kprep(const void* __restrict__ s,
                                             const void* __restrict__ sh,
                                             const int* __restrict__ hist_len,
                                             const float* __restrict__ WF,
                                             u16* __restrict__ sTx,
                                             int* __restrict__ nar,
                                             u16* __restrict__ xpartT,
                                             const int* __restrict__ flag){
  const bool isbf = (*flag != 0);
  const int t = blockIdx.y;
  const int b = blockIdx.x * 256 + threadIdx.x;
  const int hl = hist_len[b];

  const void* base; size_t soff; float zf;
  if (t == 0){ base = s;  soff = (size_t)b * SROW; zf = 1.0f; }
  else {
    base = sh; soff = ((size_t)b * 2 + ((t == 1) ? 1 : 0)) * SROW;
    zf = (hl >= 2) ? 1.0f : 0.0f;
  }

  int n = 64;
  if (zf != 0.0f){
    n = 0;
    for (int r = 0; r < 64; ++r){
      float f0 = ldin(base, soff + 7 + 6 * r, isbf);
      n += isnanf32(f0) ? 0 : 1;
    }
    for (int r = 0; r < 64; ++r){
      u16 v[6];
      #pragma unroll
      for (int i = 0; i < 6; ++i){
        float f = ldin(base, soff + 7 + 6 * r + i, isbf);
        f = isnanf32(f) ? 0.0f : f;
        v[i] = f2bf(f);
      }
      uint4 w;
      w.x = (uint)v[0] | ((uint)v[1] << 16);
      w.y = (uint)v[2] | ((uint)v[3] << 16);
      w.z = (uint)v[4] | ((uint)v[5] << 16);
      w.w = 0u;
      *(uint4*)&sTx[(((size_t)(t * 64 + r)) * NB + b) * 8] = w;
    }
  }
  nar[t * NB + b] = n;

  float sOS[7];
  #pragma unroll
  for (int i = 0; i < 7; ++i) sOS[i] = ldin(base, soff + i, isbf) * zf;
  const float* wos = WF + t * TW + W_WOS;
  const float* bos = WF + t * TW + W_BOS;
  u16* xo = xpartT + ((size_t)(t * NB + b)) * 128;
  for (int j = 0; j < 64; ++j){
    float acc = bos[j];
    #pragma unroll
    for (int i = 0; i < 7; ++i) acc = fmaf(wos[j * 7 + i], sOS[i], acc);
    xo[j] = f2bf(fmaxf(acc, 0.0f));
  }
}

// ---------- counting sort by n (ascending), compaction to participating batches ----------
__global__ void khist(const int* __restrict__ hist_len, const int* __restrict__ nar,
                      int* __restrict__ hist){
  const int t = blockIdx.y;
  const int b = blockIdx.x * 256 + threadIdx.x;
  if (t > 0 && hist_len[b] < 2) return;
  int key = nar[t * NB + b]; key = min(max(key, 0), 64);
  atomicAdd(&hist[t * 65 + key], 1);
}
__global__ void kscan(const int* __restrict__ hist, int* __restrict__ offs, int* __restrict__ cnt){
  const int t = threadIdx.x;
  if (t >= 3) return;
  int acc = 0;
  for (int k = 0; k < 65; ++k){ offs[t * 65 + k] = acc; acc += hist[t * 65 + k]; }
  cnt[t] = acc;
}
__global__ void kscatter(const int* __restrict__ hist_len, const int* __restrict__ nar,
                         int* __restrict__ offs, int* __restrict__ idx){
  const int t = blockIdx.y;
  const int b = blockIdx.x * 256 + threadIdx.x;
  if (t > 0 && hist_len[b] < 2) return;
  int key = nar[t * NB + b]; key = min(max(key, 0), 64);
  int pos = atomicAdd(&offs[t * 65 + key], 1);
  idx[t * NB + pos] = b;
}
__global__ void kpad(const int* __restrict__ cnt, int* __restrict__ idx){
  const int t = blockIdx.x;
  const int c = cnt[t];
  if (c == 0) return;
  const int pad = (c + 63) & ~63;
  const int last = idx[t * NB + c - 1];
  for (int i = c + threadIdx.x; i < pad; i += 64) idx[t * NB + i] = last;
}

// ---------- kernel M: inner LSTM via MFMA, sorted+compacted, early exit, dbuf h ----------
__global__ __launch_bounds__(256) void kmainM(const int* __restrict__ nar,
                                              const float* __restrict__ WF,
                                              const u16* __restrict__ sTx,
                                              u16* __restrict__ xpartT,
                                              const int* __restrict__ idx,
                                              const int* __restrict__ cnt,
                                              float* __restrict__ ztraj){
  __shared__ u16 hHi[2][64 * 72];
  __shared__ u16 hLo[2][64 * 72];
  __shared__ float zh[64];
  __shared__ float zg[4][64];
  const int t = blockIdx.y;
  const float* Wt = WF + t * TW;

  // ---- special block: zero-input trajectory (t=1,2), batch-independent ----
  if (blockIdx.x == 128){
    if (t == 0) return;
    const int u = threadIdx.x & 63;
    const int w = threadIdx.x >> 6;
    const float* wr = Wt + W_WHH + (w * 64 + u) * 64;
    const float bsu = Wt[W_BSUM + w * 64 + u];
    if (w == 0) zh[u] = 0.0f;
    float zc = 0.0f;
    __syncthreads();
    for (int step = 0; step < 64; ++step){
      float a0 = 0.0f, a1 = 0.0f, a2 = 0.0f, a3 = 0.0f;
      #pragma unroll
      for (int k = 0; k < 64; k += 4){
        a0 = fmaf(wr[k],     zh[k],     a0);
        a1 = fmaf(wr[k + 1], zh[k + 1], a1);
        a2 = fmaf(wr[k + 2], zh[k + 2], a2);
        a3 = fmaf(wr[k + 3], zh[k + 3], a3);
      }
      zg[w][u] = bsu + (a0 + a1) + (a2 + a3);
      __syncthreads();
      if (w == 0){
        float gi = zg[0][u], gf = zg[1][u], gg = zg[2][u], go = zg[3][u];
        zc = sigm(gf) * zc + sigm(gi) * tanh_f(gg);
        zh[u] = sigm(go) * tanh_f(zc);
      }
      __syncthreads();
    }
    if (w == 0){
      float acc = Wt[W_BTS + u];
      const float* wts = Wt + W_WTS + u * 64;
      for (int k = 0; k < 64; ++k) acc = fmaf(wts[k], zh[k], acc);
      ztraj[(t - 1) * 64 + u] = fmaxf(acc, 0.0f);
    }
    return;
  }

  const int c = cnt[t];
  if (blockIdx.x * 64 >= c) return;

  const int lane = threadIdx.x & 63;
  const int q    = __builtin_amdgcn_readfirstlane((int)(threadIdx.x >> 6));
  const int nlo  = lane & 15;
  const int quad = lane >> 4;

  for (int i = threadIdx.x; i < 64 * 72; i += 256){
    hHi[0][i] = 0; hLo[0][i] = 0;
  }

  // A-fragments (resident): Whh (2 K-frags) + Wih per gate, biases
  short8 aW[4][2], aX[4];
  float4v binit[4];
  #pragma unroll
  for (int g = 0; g < 4; ++g){
    const int mrow = g * 64 + q * 16 + nlo;
    const float* wr = Wt + W_WHH + mrow * 64;
    #pragma unroll
    for (int f = 0; f < 2; ++f){
      const int k0 = f * 32 + quad * 8;
      short8 a;
      #pragma unroll
      for (int j = 0; j < 8; ++j) a[j] = (short)f2bf(wr[k0 + j]);
      aW[g][f] = a;
    }
    const float* wi = Wt + W_WIH + mrow * 6;
    short8 ax = {0, 0, 0, 0, 0, 0, 0, 0};
    if (quad == 0){
      #pragma unroll
      for (int j = 0; j < 6; ++j) ax[j] = (short)f2bf(wi[j]);
    }
    aX[g] = ax;
    binit[g] = *(const float4v*)(Wt + W_BSUM + g * 64 + q * 16 + quad * 4);
  }

  int bb4[4], n4[4];
  #pragma unroll
  for (int nt = 0; nt < 4; ++nt){
    bb4[nt] = idx[t * NB + blockIdx.x * 64 + nt * 16 + nlo];
    n4[nt]  = nar[t * NB + bb4[nt]];
  }
  // block max n (sorted -> tight); all waves see same 64 batches -> consistent
  int nmax = max(max(n4[0], n4[1]), max(n4[2], n4[3]));
  #pragma unroll
  for (int o = 1; o < 16; o <<= 1) nmax = max(nmax, __shfl_xor(nmax, o));

  float c_st[4][4], h_st[4][4];
  #pragma unroll
  for (int nt = 0; nt < 4; ++nt)
    #pragma unroll
    for (int r = 0; r < 4; ++r){ c_st[nt][r] = 0.0f; h_st[nt][r] = 0.0f; }

  const u16* sB[4];
  #pragma unroll
  for (int nt = 0; nt < 4; ++nt)
    sB[nt] = sTx + ((size_t)(t * 64) * NB + bb4[nt]) * 8;

  __syncthreads();

  for (int step = 0; step < nmax; ++step){
    const u16* rHi = hHi[step & 1];
    const u16* rLo = hLo[step & 1];
    u16* wHi = hHi[(step + 1) & 1];
    u16* wLo = hLo[(step + 1) & 1];
    float4v acc[4][4];
    #pragma unroll
    for (int nt = 0; nt < 4; ++nt){
      short8 xf = {0, 0, 0, 0, 0, 0, 0, 0};
      if (lane < 16) xf = *(const short8*)(sB[nt] + (size_t)step * NB * 8);
      const int hb = (nt * 16 + nlo) * 72 + quad * 8;
      short8 h0 = *(const short8*)&rHi[hb];
      short8 h1 = *(const short8*)&rHi[hb + 32];
      short8 l0 = *(const short8*)&rLo[hb];
      short8 l1 = *(const short8*)&rLo[hb + 32];
      #pragma unroll
      for (int g = 0; g < 4; ++g){
        float4v a = binit[g];
        a = MFMA16(aX[g], xf, a);
        a = MFMA16(aW[g][0], h0, a);
        a = MFMA16(aW[g][1], h1, a);
        a = MFMA16(aW[g][0], l0, a);
        a = MFMA16(aW[g][1], l1, a);
        acc[g][nt] = a;
      }
    }
    #pragma unroll
    for (int nt = 0; nt < 4; ++nt){
      const bool v = (step < n4[nt]);
      u16 hb4[4], lb4[4];
      #pragma unroll
      for (int r = 0; r < 4; ++r){
        float gi = acc[0][nt][r], gf = acc[1][nt][r], gg = acc[2][nt][r], go = acc[3][nt][r];
        float cn = sigm(gf) * c_st[nt][r] + sigm(gi) * tanh_f(gg);
        float hn = sigm(go) * tanh_f(cn);
        c_st[nt][r] = v ? cn : c_st[nt][r];
        h_st[nt][r] = v ? hn : h_st[nt][r];
        u16 hi = f2bf(h_st[nt][r]);
        float lo = h_st[nt][r] - bf2f(hi);
        hb4[r] = hi; lb4[r] = f2bf(lo);
      }
      const int off = (nt * 16 + nlo) * 72 + q * 16 + quad * 4;
      uint2 hw, lw;
      hw.x = (uint)hb4[0] | ((uint)hb4[1] << 16);
      hw.y = (uint)hb4[2] | ((uint)hb4[3] << 16);
      lw.x = (uint)lb4[0] | ((uint)lb4[1] << 16);
      lw.y = (uint)lb4[2] | ((uint)lb4[3] << 16);
      *(uint2*)&wHi[off] = hw;
      *(uint2*)&wLo[off] = lw;
    }
    __syncthreads();   // single barrier: dbuf removes WAR hazard
  }

  // xTS epilogue from final h buffer
  const u16* fHi = hHi[nmax & 1];
  const u16* fLo = hLo[nmax & 1];
  short8 aT[2];
  #pragma unroll
  for (int f = 0; f < 2; ++f){
    const float* wr = Wt + W_WTS + (q * 16 + nlo) * 64 + f * 32 + quad * 8;
    short8 a;
    #pragma unroll
    for (int j = 0; j < 8; ++j) a[j] = (short)f2bf(wr[j]);
    aT[f] = a;
  }
  float4v btsv = *(const float4v*)(Wt + W_BTS + q * 16 + quad * 4);
  #pragma unroll
  for (int nt = 0; nt < 4; ++nt){
    const int hb = (nt * 16 + nlo) * 72 + quad * 8;
    float4v a = btsv;
    a = MFMA16(aT[0], *(const short8*)&fHi[hb], a);
    a = MFMA16(aT[1], *(const short8*)&fHi[hb + 32], a);
    a = MFMA16(aT[0], *(const short8*)&fLo[hb], a);
    a = MFMA16(aT[1], *(const short8*)&fLo[hb + 32], a);
    u16 o4[4];
    #pragma unroll
    for (int r = 0; r < 4; ++r) o4[r] = f2bf(fmaxf(a[r], 0.0f));
    size_t oidx = ((size_t)(t * NB + bb4[nt])) * 128 + 64 + q * 16 + quad * 4;
    uint2 w;
    w.x = (uint)o4[0] | ((uint)o4[1] << 16);
    w.y = (uint)o4[2] | ((uint)o4[3] << 16);
    *(uint2*)&xpartT[oidx] = w;
  }
}

// ---------- kernel B: broadcast zero-trajectory xTS to hl<2 batches (t=1,2) ----------
__global__ __launch_bounds__(256) void kbcast(const int* __restrict__ hist_len,
                                              const float* __restrict__ ztraj,
                                              u16* __restrict__ xpartT){
  const int b = blockIdx.x * 256 + threadIdx.x;
  if (hist_len[b] >= 2) return;
  #pragma unroll
  for (int t = 1; t <= 2; ++t){
    u16* dst = xpartT + ((size_t)(t * NB + b)) * 128 + 64;
    const float* z = ztraj + (t - 1) * 64;
    #pragma unroll
    for (int u = 0; u < 64; u += 2){
      uint w = (uint)f2bf(z[u]) | ((uint)f2bf(z[u + 1]) << 16);
      *(uint*)&dst[u] = w;
    }
  }
}

// ---------- kernel F: outer LSTM via MFMA (3 steps) + MLP; A-frags hoisted ----------
__global__ __launch_bounds__(256) void kfinalM(const float* __restrict__ WF,
                                               const u16* __restrict__ xpartT,
                                               const int* __restrict__ hist_len,
                                               void* __restrict__ out,
                                               const int* __restrict__ flag){
  __shared__ u16 hHi[64 * 72];
  __shared__ u16 hLo[64 * 72];
  __shared__ float x1T[64 * 68];
  const bool isbf = (*flag != 0);
  const int b0   = blockIdx.x * 64;
  const int lane = threadIdx.x & 63;
  const int q    = __builtin_amdgcn_readfirstlane((int)(threadIdx.x >> 6));
  const int nlo  = lane & 15;
  const int quad = lane >> 4;

  for (int i = threadIdx.x; i < 64 * 72; i += 256){ hHi[i] = 0; hLo[i] = 0; }

  const float* WO = WF + W_OUT;
  int hl4[4];
  #pragma unroll
  for (int nt = 0; nt < 4; ++nt) hl4[nt] = hist_len[b0 + nt * 16 + nlo];

  // hoisted A-fragments
  short8 aI[4][4], aH[4][2];
  float4v bi4[4];
  #pragma unroll
  for (int g = 0; g < 4; ++g){
    const int mrow = g * 64 + q * 16 + nlo;
    #pragma unroll
    for (int f = 0; f < 4; ++f){
      const float* w = WO + WO_WIHO + mrow * 128 + f * 32 + quad * 8;
      short8 a;
      #pragma unroll
      for (int j = 0; j < 8; ++j) a[j] = (short)f2bf(w[j]);
      aI[g][f] = a;
    }
    #pragma unroll
    for (int f = 0; f < 2; ++f){
      const float* w = WO + WO_WHHO + mrow * 64 + f * 32 + quad * 8;
      short8 a;
      #pragma unroll
      for (int j = 0; j < 8; ++j) a[j] = (short)f2bf(w[j]);
      aH[g][f] = a;
    }
    bi4[g] = *(const float4v*)(WO + WO_BSUM + g * 64 + q * 16 + quad * 4);
  }

  float c_st[4][4], h_st[4][4];
  #pragma unroll
  for (int nt = 0; nt < 4; ++nt)
    #pragma unroll
    for (int r = 0; r < 4; ++r){ c_st[nt][r] = 0.0f; h_st[nt][r] = 0.0f; }
  __syncthreads();

  for (int p = 0; p < 3; ++p){
    float4v acc[4][4];
    #pragma unroll
    for (int nt = 0; nt < 4; ++nt){
      const int bb = b0 + nt * 16 + nlo;
      const int tt = 2 - ((p - hl4[nt] + 2) % 3);
      const u16* xb = xpartT + ((size_t)(tt * NB + bb)) * 128;
      short8 xf[4];
      #pragma unroll
      for (int f = 0; f < 4; ++f) xf[f] = *(const short8*)(xb + f * 32 + quad * 8);
      const int hb = (nt * 16 + nlo) * 72 + quad * 8;
      short8 h0 = *(const short8*)&hHi[hb];
      short8 h1 = *(const short8*)&hHi[hb + 32];
      short8 l0 = *(const short8*)&hLo[hb];
      short8 l1 = *(const short8*)&hLo[hb + 32];
      #pragma unroll
      for (int g = 0; g < 4; ++g){
        float4v a = bi4[g];
        #pragma unroll
        for (int f = 0; f < 4; ++f) a = MFMA16(aI[g][f], xf[f], a);
        a = MFMA16(aH[g][0], h0, a);
        a = MFMA16(aH[g][1], h1, a);
        a = MFMA16(aH[g][0], l0, a);
        a = MFMA16(aH[g][1], l1, a);
        acc[g][nt] = a;
      }
    }
    __syncthreads();
    #pragma unroll
    for (int nt = 0; nt < 4; ++nt){
      const bool v = (p <= hl4[nt]);
      u16 hb4[4], lb4[4];
      #pragma unroll
      for (int r = 0; r < 4; ++r){
        float gi = acc[0][nt][r], gf = acc[1][nt][r], gg = acc[2][nt][r], go = acc[3][nt][r];
        float cn = sigm(gf) * c_st[nt][r] + sigm(gi) * tanh_f(gg);
        float hn = sigm(go) * tanh_f(cn);
        c_st[nt][r] = v ? cn : c_st[nt][r];
        h_st[nt][r] = v ? hn : h_st[nt][r];
        u16 hi = f2bf(h_st[nt][r]);
        float lo = h_st[nt][r] - bf2f(hi);
        hb4[r] = hi; lb4[r] = f2bf(lo);
      }
      const int off = (nt * 16 + nlo) * 72 + q * 16 + quad * 4;
      uint2 hw, lw;
      hw.x = (uint)hb4[0] | ((uint)hb4[1] << 16);
      hw.y = (uint)hb4[2] | ((uint)hb4[3] << 16);
      lw.x = (uint)lb4[0] | ((uint)lb4[1] << 16);
      lw.y = (uint)lb4[2] | ((uint)lb4[3] << 16);
      *(uint2*)&hHi[off] = hw;
      *(uint2*)&hLo[off] = lw;
    }
    __syncthreads();
  }

  // x1 = relu(W1 @ hidden + b1) via MFMA
  short8 a1[2];
  #pragma unroll
  for (int f = 0; f < 2; ++f){
    const float* w = WO + WO_W1 + (q * 16 + nlo) * 64 + f * 32 + quad * 8;
    short8 a;
    #pragma unroll
    for (int j = 0; j < 8; ++j) a[j] = (short)f2bf(w[j]);
    a1[f] = a;
  }
  float4v b1v = *(const float4v*)(WO + WO_B1 + q * 16 + quad * 4);
  #pragma unroll
  for (int nt = 0; nt < 4; ++nt){
    const int hb = (nt * 16 + nlo) * 72 + quad * 8;
    float4v a = b1v;
    a = MFMA16(a1[0], *(const short8*)&hHi[hb], a);
    a = MFMA16(a1[1], *(const short8*)&hHi[hb + 32], a);
    a = MFMA16(a1[0], *(const short8*)&hLo[hb], a);
    a = MFMA16(a1[1], *(const short8*)&hLo[hb + 32], a);
    float4v rv;
    #pragma unroll
    for (int r = 0; r < 4; ++r) rv[r] = fmaxf(a[r], 0.0f);
    *(float4v*)&x1T[(nt * 16 + nlo) * 68 + q * 16 + quad * 4] = rv;
  }
  __syncthreads();

  const int bloc = threadIdx.x >> 2;
  const int r0 = threadIdx.x & 3;
  const float* w2 = WO + WO_W2;
  const float* b2 = WO + WO_B2;
  for (int r = r0; r < 9; r += 4){
    float acc = b2[r];
    const float* wr = w2 + r * 64;
    #pragma unroll
    for (int k = 0; k < 64; ++k) acc = fmaf(wr[k], x1T[bloc * 68 + k], acc);
    if (isbf) ((u16*)out)[(size_t)(b0 + bloc) * 9 + r] = f2bf(acc);
    else      ((float*)out)[(size_t)(b0 + bloc) * 9 + r] = acc;
  }
}

extern "C" void kernel_launch(void* const* d_in, const int* in_sizes, int n_in,
                              void* d_out, int out_size, void* d_ws, size_t ws_size,
                              hipStream_t stream){
  char* ws = (char*)d_ws;
  float* WF = (float*)ws;
  size_t off = ((size_t)WF_TOTAL * 4 + 255) & ~(size_t)255;
  u16* sTx = (u16*)(ws + off);    off += (size_t)3 * 64 * NB * 8 * 2;
  u16* xpartT = (u16*)(ws + off); off += (size_t)3 * NB * 128 * 2;
  int* nar = (int*)(ws + off);    off += (size_t)3 * NB * 4;
  int* flag = (int*)(ws + off);   off += 256;
  int* hist = (int*)(ws + off);   off += 3 * 65 * 4;
  int* cnt  = (int*)(ws + off);   off += 3 * 4;
  int* offs = (int*)(ws + off);   off += 3 * 65 * 4;
  int* idx  = (int*)(ws + off);   off += (size_t)3 * NB * 4;
  float* ztraj = (float*)(ws + off); off += 2 * 64 * 4;

  PtrTab P;
  for (int i = 0; i < 36; ++i) P.p[i] = d_in[i];

  SegTab S;
  int si = 0;
  for (int t = 0; t < 3; ++t){
    int base = 4 + 8 * t;
    int d = t * TW;
    S.s[si++] = { base + 2, -1,       d + W_WIH,  1536  };
    S.s[si++] = { base + 3, -1,       d + W_WHH,  16384 };
    S.s[si++] = { base + 4, base + 5, d + W_BSUM, 256   };
    S.s[si++] = { base + 6, -1,       d + W_WTS,  4096  };
    S.s[si++] = { base + 7, -1,       d + W_BTS,  64    };
    S.s[si++] = { base + 0, -1,       d + W_WOS,  448   };
    S.s[si++] = { base + 1, -1,       d + W_BOS,  64    };
  }
  {
    int O = W_OUT;
    S.s[si++] = { 28, -1, O + WO_WIHO, 32768 };
    S.s[si++] = { 29, -1, O + WO_WHHO, 16384 };
    S.s[si++] = { 30, 31, O + WO_BSUM, 256   };
    S.s[si++] = { 32, -1, O + WO_W1,   4096  };
    S.s[si++] = { 33, -1, O + WO_B1,   64    };
    S.s[si++] = { 34, -1, O + WO_W2,   576   };
    S.s[si++] = { 35, -1, O + WO_B2,   9     };
  }

  const int* hl_ptr = (const int*)d_in[3];

  kdetect<<<dim3(1), 64, 0, stream>>>(d_in[7], flag);
  kweights<<<dim3(28), 256, 0, stream>>>(P, S, WF, flag);
  kprep<<<dim3(NB / 256, 3), 256, 0, stream>>>(d_in[0], d_in[1], hl_ptr, WF, sTx, nar, xpartT, flag);
  hipMemsetAsync(hist, 0, (3 * 65 + 3) * 4, stream);
  khist<<<dim3(NB / 256, 3), 256, 0, stream>>>(hl_ptr, nar, hist);
  kscan<<<dim3(1), 64, 0, stream>>>(hist, offs, cnt);
  kscatter<<<dim3(NB / 256, 3), 256, 0, stream>>>(hl_ptr, nar, offs, idx);
  kpad<<<dim3(3), 64, 0, stream>>>(cnt, idx);
  kmainM<<<dim3(129, 3), 256, 0, stream>>>(nar, WF, sTx, xpartT, idx, cnt, ztraj);
  kbcast<<<dim3(NB / 256), 256, 0, stream>>>(hl_ptr, ztraj, xpartT);
  kfinalM<<<dim3(NB / 64), 256, 0, stream>>>(WF, xpartT, hl_ptr, d_out, flag);
}

// Round 9
// 621.658 us; speedup vs baseline: 7.8951x; 1.1027x over previous
//
#include <hip/hip_runtime.h>
#include <hip/hip_bf16.h>

#define NB 8192
#define SROW 391

// ---- weight ws layout (floats) ----
#define TW      22848
#define W_WIH   0
#define W_WHH   1536
#define W_BSUM  17920
#define W_WTS   18176
#define W_BTS   22272
#define W_WOS   22336
#define W_BOS   22784
#define W_OUT   68544
#define WO_WIHO 0
#define WO_WHHO 32768
#define WO_BSUM 49152
#define WO_W1   49408
#define WO_B1   53504
#define WO_W2   53568
#define WO_B2   54144
#define WF_TOTAL 122697

typedef unsigned short u16;
typedef __attribute__((ext_vector_type(8))) short short8;
typedef __attribute__((ext_vector_type(4))) float float4v;

#define MFMA16(a, b, c) __builtin_amdgcn_mfma_f32_16x16x32_bf16((a), (b), (c), 0, 0, 0)

__device__ __forceinline__ float bf2f(u16 u){ return __uint_as_float(((unsigned)u) << 16); }
__device__ __forceinline__ u16 f2bf(float f){
  unsigned x = __float_as_uint(f);
  unsigned r = (x + 0x7FFFu + ((x >> 16) & 1u)) >> 16;   // RNE
  return (u16)r;
}
__device__ __forceinline__ bool isnanf32(float f){
  unsigned x = __float_as_uint(f);
  return (x & 0x7FFFFFFFu) > 0x7F800000u;
}
__device__ __forceinline__ float ldin(const void* p, size_t i, bool isbf){
  if (isbf) return bf2f(((const u16*)p)[i]);
  return ((const float*)p)[i];
}
__device__ __forceinline__ float sigm(float x){ return __fdividef(1.0f, 1.0f + __expf(-x)); }
__device__ __forceinline__ float tanh_f(float x){ return __fdividef(2.0f, 1.0f + __expf(-2.0f * x)) - 1.0f; }

struct Seg { int src; int src2; int dst; int n; };
struct SegTab { Seg s[28]; };
struct PtrTab { const void* p[36]; };

// ---------- kernel D: detect input dtype from Whh0 bit patterns ----------
__global__ void kdetect(const void* whh0, int* flag){
  if (threadIdx.x == 0 && blockIdx.x == 0){
    const u16* u = (const u16*)whh0;
    int cnt = 0;
    for (int i = 0; i < 128; i += 2){
      int e = (u[i] >> 7) & 0xFF;
      cnt += (e >= 100 && e <= 141) ? 1 : 0;
    }
    *flag = (cnt >= 32) ? 1 : 0;
  }
}

// ---------- kernel W: convert weights -> fp32 into ws ----------
__global__ __launch_bounds__(256) void kweights(PtrTab P, SegTab S, float* __restrict__ WF,
                                                const int* __restrict__ flag){
  const bool isbf = (*flag != 0);
  Seg sg = S.s[blockIdx.x];
  const void* a = P.p[sg.src];
  const void* b = (sg.src2 >= 0) ? P.p[sg.src2] : nullptr;
  for (int i = threadIdx.x; i < sg.n; i += 256){
    float v = ldin(a, i, isbf);
    if (b) v += ldin(b, i, isbf);
    WF[sg.dst + i] = v;
  }
}

// ---------- kernel P: sTx[t][step][b][8] bf16 (only nonzero seqs), nar, xOS ----------
__global__ __launch_bounds__(256) void kprep(const void* __restrict__ s,
                                             const void* __restrict__ sh,
                                             const int* __restrict__ hist_len,
                                             const float* __restrict__ WF,
                                             u16* __restrict__ sTx,
                                             int* __restrict__ nar,
                                             u16* __restrict__ xpartT,
                                             const int* __restrict__ flag){
  const bool isbf = (*flag != 0);
  const int t = blockIdx.y;
  const int b = blockIdx.x * 256 + threadIdx.x;
  const int hl = hist_len[b];

  const void* base; size_t soff; float zf;
  if (t == 0){ base = s;  soff = (size_t)b * SROW; zf = 1.0f; }
  else {
    base = sh; soff = ((size_t)b * 2 + ((t == 1) ? 1 : 0)) * SROW;
    zf = (hl >= 2) ? 1.0f : 0.0f;
  }

  int n = 64;
  if (zf != 0.0f){
    n = 0;
    for (int r = 0; r < 64; ++r){
      float sv6[6];
      if (isbf){
        u16 tmp[6];
        __builtin_memcpy(tmp, (const u16*)base + soff + 7 + 6 * r, 12);
        #pragma unroll
        for (int i = 0; i < 6; ++i) sv6[i] = bf2f(tmp[i]);
      } else {
        __builtin_memcpy(sv6, (const float*)base + soff + 7 + 6 * r, 24);
      }
      n += isnanf32(sv6[0]) ? 0 : 1;
      u16 v[6];
      #pragma unroll
      for (int i = 0; i < 6; ++i) v[i] = f2bf(isnanf32(sv6[i]) ? 0.0f : sv6[i]);
      uint4 w;
      w.x = (uint)v[0] | ((uint)v[1] << 16);
      w.y = (uint)v[2] | ((uint)v[3] << 16);
      w.z = (uint)v[4] | ((uint)v[5] << 16);
      w.w = 0u;
      *(uint4*)&sTx[(((size_t)(t * 64 + r)) * NB + b) * 8] = w;
    }
  }
  nar[t * NB + b] = n;

  float sOS[7];
  #pragma unroll
  for (int i = 0; i < 7; ++i) sOS[i] = ldin(base, soff + i, isbf) * zf;
  const float* wos = WF + t * TW + W_WOS;
  const float* bos = WF + t * TW + W_BOS;
  u16* xo = xpartT + ((size_t)(t * NB + b)) * 128;
  for (int j = 0; j < 64; ++j){
    float acc = bos[j];
    #pragma unroll
    for (int i = 0; i < 7; ++i) acc = fmaf(wos[j * 7 + i], sOS[i], acc);
    xo[j] = f2bf(fmaxf(acc, 0.0f));
  }
}

// ---------- counting sort by n (ascending), compaction to participating batches ----------
__global__ void khist(const int* __restrict__ hist_len, const int* __restrict__ nar,
                      int* __restrict__ hist){
  const int t = blockIdx.y;
  const int b = blockIdx.x * 256 + threadIdx.x;
  if (t > 0 && hist_len[b] < 2) return;
  int key = nar[t * NB + b]; key = min(max(key, 0), 64);
  atomicAdd(&hist[t * 65 + key], 1);
}
__global__ void kscan(const int* __restrict__ hist, int* __restrict__ offs, int* __restrict__ cnt){
  const int t = threadIdx.x;
  if (t >= 3) return;
  int acc = 0;
  for (int k = 0; k < 65; ++k){ offs[t * 65 + k] = acc; acc += hist[t * 65 + k]; }
  cnt[t] = acc;
}
__global__ void kscatter(const int* __restrict__ hist_len, const int* __restrict__ nar,
                         int* __restrict__ offs, int* __restrict__ idx){
  const int t = blockIdx.y;
  const int b = blockIdx.x * 256 + threadIdx.x;
  if (t > 0 && hist_len[b] < 2) return;
  int key = nar[t * NB + b]; key = min(max(key, 0), 64);
  int pos = atomicAdd(&offs[t * 65 + key], 1);
  idx[t * NB + pos] = b;
}
__global__ void kpad(const int* __restrict__ cnt, int* __restrict__ idx){
  const int t = blockIdx.x;
  const int c = cnt[t];
  if (c == 0) return;
  const int pad = (c + 63) & ~63;
  const int last = idx[t * NB + c - 1];
  for (int i = c + threadIdx.x; i < pad; i += 64) idx[t * NB + i] = last;
}

// ---------- kernel M: round-6-exact 256-thread layout + x prefetch only ----------
__global__ __launch_bounds__(256) void kmainM(const int* __restrict__ nar,
                                              const float* __restrict__ WF,
                                              const u16* __restrict__ sTx,
                                              u16* __restrict__ xpartT,
                                              const int* __restrict__ idx,
                                              const int* __restrict__ cnt,
                                              float* __restrict__ ztraj){
  __shared__ u16 hHi[2][64 * 72];
  __shared__ u16 hLo[2][64 * 72];
  __shared__ float zh[64];
  __shared__ float zg[256];
  const int t = blockIdx.y;
  const float* Wt = WF + t * TW;

  // ---- special block: zero-input trajectory (t=1,2), batch-independent ----
  if (blockIdx.x == 128){
    if (t == 0) return;
    const int u = threadIdx.x & 63;
    const int w = threadIdx.x >> 6;
    const int row = w * 64 + u;
    const float* wr = Wt + W_WHH + row * 64;
    const float bsu = Wt[W_BSUM + row];
    if (w == 0) zh[u] = 0.0f;
    float zc = 0.0f;
    __syncthreads();
    for (int step = 0; step < 64; ++step){
      float a0 = 0.0f, a1 = 0.0f, a2 = 0.0f, a3 = 0.0f;
      #pragma unroll
      for (int k = 0; k < 64; k += 4){
        a0 = fmaf(wr[k],     zh[k],     a0);
        a1 = fmaf(wr[k + 1], zh[k + 1], a1);
        a2 = fmaf(wr[k + 2], zh[k + 2], a2);
        a3 = fmaf(wr[k + 3], zh[k + 3], a3);
      }
      zg[row] = bsu + (a0 + a1) + (a2 + a3);
      __syncthreads();
      if (w == 0){
        float gi = zg[u], gf = zg[64 + u], gg = zg[128 + u], go = zg[192 + u];
        zc = sigm(gf) * zc + sigm(gi) * tanh_f(gg);
        zh[u] = sigm(go) * tanh_f(zc);
      }
      __syncthreads();
    }
    if (w == 0){
      float acc = Wt[W_BTS + u];
      const float* wts = Wt + W_WTS + u * 64;
      for (int k = 0; k < 64; ++k) acc = fmaf(wts[k], zh[k], acc);
      ztraj[(t - 1) * 64 + u] = fmaxf(acc, 0.0f);
    }
    return;
  }

  const int c = cnt[t];
  if (blockIdx.x * 64 >= c) return;

  const int lane = threadIdx.x & 63;
  const int q    = __builtin_amdgcn_readfirstlane((int)(threadIdx.x >> 6));
  const int nlo  = lane & 15;
  const int quad = lane >> 4;

  for (int i = threadIdx.x; i < 64 * 72; i += 256){ hHi[0][i] = 0; hLo[0][i] = 0; }

  // A-fragments (resident)
  short8 aW[4][2], aX[4];
  float4v binit[4];
  #pragma unroll
  for (int g = 0; g < 4; ++g){
    const int mrow = g * 64 + q * 16 + nlo;
    const float* wr = Wt + W_WHH + mrow * 64;
    #pragma unroll
    for (int f = 0; f < 2; ++f){
      const int k0 = f * 32 + quad * 8;
      short8 a;
      #pragma unroll
      for (int j = 0; j < 8; ++j) a[j] = (short)f2bf(wr[k0 + j]);
      aW[g][f] = a;
    }
    const float* wi = Wt + W_WIH + mrow * 6;
    short8 ax = {0, 0, 0, 0, 0, 0, 0, 0};
    if (quad == 0){
      #pragma unroll
      for (int j = 0; j < 6; ++j) ax[j] = (short)f2bf(wi[j]);
    }
    aX[g] = ax;
    binit[g] = *(const float4v*)(Wt + W_BSUM + g * 64 + q * 16 + quad * 4);
  }

  int bb4[4], n4[4];
  #pragma unroll
  for (int nt = 0; nt < 4; ++nt){
    bb4[nt] = idx[t * NB + blockIdx.x * 64 + nt * 16 + nlo];
    n4[nt]  = nar[t * NB + bb4[nt]];
  }
  int nmax = max(max(n4[0], n4[1]), max(n4[2], n4[3]));
  #pragma unroll
  for (int o = 1; o < 16; o <<= 1) nmax = max(nmax, __shfl_xor(nmax, o));

  float c_st[4][4], h_st[4][4];
  #pragma unroll
  for (int nt = 0; nt < 4; ++nt)
    #pragma unroll
    for (int r = 0; r < 4; ++r){ c_st[nt][r] = 0.0f; h_st[nt][r] = 0.0f; }

  const u16* sB[4];
  #pragma unroll
  for (int nt = 0; nt < 4; ++nt)
    sB[nt] = sTx + ((size_t)(t * 64) * NB + bb4[nt]) * 8;

  // prefetch step-0 x fragments (same values/order as round 6, just loaded early)
  short8 xcur[4], xnxt[4];
  #pragma unroll
  for (int nt = 0; nt < 4; ++nt){
    short8 xf = {0, 0, 0, 0, 0, 0, 0, 0};
    if (lane < 16) xf = *(const short8*)sB[nt];
    xcur[nt] = xf;
  }

  __syncthreads();

  for (int step = 0; step < nmax; ++step){
    const int ns = min(step + 1, 63);
    #pragma unroll
    for (int nt = 0; nt < 4; ++nt){
      short8 xf = {0, 0, 0, 0, 0, 0, 0, 0};
      if (lane < 16) xf = *(const short8*)(sB[nt] + (size_t)ns * NB * 8);
      xnxt[nt] = xf;
    }

    const u16* rHi = hHi[step & 1];
    const u16* rLo = hLo[step & 1];
    u16* wHi = hHi[(step + 1) & 1];
    u16* wLo = hLo[(step + 1) & 1];
    float4v acc[4][4];
    #pragma unroll
    for (int nt = 0; nt < 4; ++nt){
      const int hb = (nt * 16 + nlo) * 72 + quad * 8;
      short8 h0 = *(const short8*)&rHi[hb];
      short8 h1 = *(const short8*)&rHi[hb + 32];
      short8 l0 = *(const short8*)&rLo[hb];
      short8 l1 = *(const short8*)&rLo[hb + 32];
      #pragma unroll
      for (int g = 0; g < 4; ++g){
        float4v a = binit[g];
        a = MFMA16(aX[g], xcur[nt], a);     // round-6 order: x first
        a = MFMA16(aW[g][0], h0, a);
        a = MFMA16(aW[g][1], h1, a);
        a = MFMA16(aW[g][0], l0, a);
        a = MFMA16(aW[g][1], l1, a);
        acc[g][nt] = a;
      }
    }
    #pragma unroll
    for (int nt = 0; nt < 4; ++nt){
      const bool v = (step < n4[nt]);
      u16 hb4[4], lb4[4];
      #pragma unroll
      for (int r = 0; r < 4; ++r){
        float gi = acc[0][nt][r], gf = acc[1][nt][r], gg = acc[2][nt][r], go = acc[3][nt][r];
        float cn = sigm(gf) * c_st[nt][r] + sigm(gi) * tanh_f(gg);
        float hn = sigm(go) * tanh_f(cn);
        c_st[nt][r] = v ? cn : c_st[nt][r];
        h_st[nt][r] = v ? hn : h_st[nt][r];
        u16 hi = f2bf(h_st[nt][r]);
        float lo = h_st[nt][r] - bf2f(hi);
        hb4[r] = hi; lb4[r] = f2bf(lo);
      }
      const int off = (nt * 16 + nlo) * 72 + q * 16 + quad * 4;
      uint2 hw, lw;
      hw.x = (uint)hb4[0] | ((uint)hb4[1] << 16);
      hw.y = (uint)hb4[2] | ((uint)hb4[3] << 16);
      lw.x = (uint)lb4[0] | ((uint)lb4[1] << 16);
      lw.y = (uint)lb4[2] | ((uint)lb4[3] << 16);
      *(uint2*)&wHi[off] = hw;
      *(uint2*)&wLo[off] = lw;
    }
    #pragma unroll
    for (int nt = 0; nt < 4; ++nt) xcur[nt] = xnxt[nt];
    __syncthreads();
  }

  // xTS epilogue from final h buffer
  const u16* fHi = hHi[nmax & 1];
  const u16* fLo = hLo[nmax & 1];
  short8 aT[2];
  #pragma unroll
  for (int f = 0; f < 2; ++f){
    const float* wr = Wt + W_WTS + (q * 16 + nlo) * 64 + f * 32 + quad * 8;
    short8 a;
    #pragma unroll
    for (int j = 0; j < 8; ++j) a[j] = (short)f2bf(wr[j]);
    aT[f] = a;
  }
  float4v btsv = *(const float4v*)(Wt + W_BTS + q * 16 + quad * 4);
  #pragma unroll
  for (int nt = 0; nt < 4; ++nt){
    const int hb = (nt * 16 + nlo) * 72 + quad * 8;
    float4v a = btsv;
    a = MFMA16(aT[0], *(const short8*)&fHi[hb], a);
    a = MFMA16(aT[1], *(const short8*)&fHi[hb + 32], a);
    a = MFMA16(aT[0], *(const short8*)&fLo[hb], a);
    a = MFMA16(aT[1], *(const short8*)&fLo[hb + 32], a);
    u16 o4[4];
    #pragma unroll
    for (int r = 0; r < 4; ++r) o4[r] = f2bf(fmaxf(a[r], 0.0f));
    size_t oidx = ((size_t)(t * NB + bb4[nt])) * 128 + 64 + q * 16 + quad * 4;
    uint2 w;
    w.x = (uint)o4[0] | ((uint)o4[1] << 16);
    w.y = (uint)o4[2] | ((uint)o4[3] << 16);
    *(uint2*)&xpartT[oidx] = w;
  }
}

// ---------- kernel B: broadcast zero-trajectory xTS to hl<2 batches (t=1,2) ----------
__global__ __launch_bounds__(256) void kbcast(const int* __restrict__ hist_len,
                                              const float* __restrict__ ztraj,
                                              u16* __restrict__ xpartT){
  const int b = blockIdx.x * 256 + threadIdx.x;
  if (hist_len[b] >= 2) return;
  #pragma unroll
  for (int t = 1; t <= 2; ++t){
    u16* dst = xpartT + ((size_t)(t * NB + b)) * 128 + 64;
    const float* z = ztraj + (t - 1) * 64;
    #pragma unroll
    for (int u = 0; u < 64; u += 2){
      uint w = (uint)f2bf(z[u]) | ((uint)f2bf(z[u + 1]) << 16);
      *(uint*)&dst[u] = w;
    }
  }
}

// ---------- kernel F: outer LSTM via MFMA (3 steps) + MLP; A-frags hoisted ----------
__global__ __launch_bounds__(256) void kfinalM(const float* __restrict__ WF,
                                               const u16* __restrict__ xpartT,
                                               const int* __restrict__ hist_len,
                                               void* __restrict__ out,
                                               const int* __restrict__ flag){
  __shared__ u16 hHi[64 * 72];
  __shared__ u16 hLo[64 * 72];
  __shared__ float x1T[64 * 68];
  const bool isbf = (*flag != 0);
  const int b0   = blockIdx.x * 64;
  const int lane = threadIdx.x & 63;
  const int q    = __builtin_amdgcn_readfirstlane((int)(threadIdx.x >> 6));
  const int nlo  = lane & 15;
  const int quad = lane >> 4;

  for (int i = threadIdx.x; i < 64 * 72; i += 256){ hHi[i] = 0; hLo[i] = 0; }

  const float* WO = WF + W_OUT;
  int hl4[4];
  #pragma unroll
  for (int nt = 0; nt < 4; ++nt) hl4[nt] = hist_len[b0 + nt * 16 + nlo];

  short8 aI[4][4], aH[4][2];
  float4v bi4[4];
  #pragma unroll
  for (int g = 0; g < 4; ++g){
    const int mrow = g * 64 + q * 16 + nlo;
    #pragma unroll
    for (int f = 0; f < 4; ++f){
      const float* w = WO + WO_WIHO + mrow * 128 + f * 32 + quad * 8;
      short8 a;
      #pragma unroll
      for (int j = 0; j < 8; ++j) a[j] = (short)f2bf(w[j]);
      aI[g][f] = a;
    }
    #pragma unroll
    for (int f = 0; f < 2; ++f){
      const float* w = WO + WO_WHHO + mrow * 64 + f * 32 + quad * 8;
      short8 a;
      #pragma unroll
      for (int j = 0; j < 8; ++j) a[j] = (short)f2bf(w[j]);
      aH[g][f] = a;
    }
    bi4[g] = *(const float4v*)(WO + WO_BSUM + g * 64 + q * 16 + quad * 4);
  }

  float c_st[4][4], h_st[4][4];
  #pragma unroll
  for (int nt = 0; nt < 4; ++nt)
    #pragma unroll
    for (int r = 0; r < 4; ++r){ c_st[nt][r] = 0.0f; h_st[nt][r] = 0.0f; }
  __syncthreads();

  for (int p = 0; p < 3; ++p){
    float4v acc[4][4];
    #pragma unroll
    for (int nt = 0; nt < 4; ++nt){
      const int bb = b0 + nt * 16 + nlo;
      const int tt = 2 - ((p - hl4[nt] + 2) % 3);
      const u16* xb = xpartT + ((size_t)(tt * NB + bb)) * 128;
      short8 xf[4];
      #pragma unroll
      for (int f = 0; f < 4; ++f) xf[f] = *(const short8*)(xb + f * 32 + quad * 8);
      const int hb = (nt * 16 + nlo) * 72 + quad * 8;
      short8 h0 = *(const short8*)&hHi[hb];
      short8 h1 = *(const short8*)&hHi[hb + 32];
      short8 l0 = *(const short8*)&hLo[hb];
      short8 l1 = *(const short8*)&hLo[hb + 32];
      #pragma unroll
      for (int g = 0; g < 4; ++g){
        float4v a = bi4[g];
        #pragma unroll
        for (int f = 0; f < 4; ++f) a = MFMA16(aI[g][f], xf[f], a);
        a = MFMA16(aH[g][0], h0, a);
        a = MFMA16(aH[g][1], h1, a);
        a = MFMA16(aH[g][0], l0, a);
        a = MFMA16(aH[g][1], l1, a);
        acc[g][nt] = a;
      }
    }
    __syncthreads();
    #pragma unroll
    for (int nt = 0; nt < 4; ++nt){
      const bool v = (p <= hl4[nt]);
      u16 hb4[4], lb4[4];
      #pragma unroll
      for (int r = 0; r < 4; ++r){
        float gi = acc[0][nt][r], gf = acc[1][nt][r], gg = acc[2][nt][r], go = acc[3][nt][r];
        float cn = sigm(gf) * c_st[nt][r] + sigm(gi) * tanh_f(gg);
        float hn = sigm(go) * tanh_f(cn);
        c_st[nt][r] = v ? cn : c_st[nt][r];
        h_st[nt][r] = v ? hn : h_st[nt][r];
        u16 hi = f2bf(h_st[nt][r]);
        float lo = h_st[nt][r] - bf2f(hi);
        hb4[r] = hi; lb4[r] = f2bf(lo);
      }
      const int off = (nt * 16 + nlo) * 72 + q * 16 + quad * 4;
      uint2 hw, lw;
      hw.x = (uint)hb4[0] | ((uint)hb4[1] << 16);
      hw.y = (uint)hb4[2] | ((uint)hb4[3] << 16);
      lw.x = (uint)lb4[0] | ((uint)lb4[1] << 16);
      lw.y = (uint)lb4[2] | ((uint)lb4[3] << 16);
      *(uint2*)&hHi[off] = hw;
      *(uint2*)&hLo[off] = lw;
    }
    __syncthreads();
  }

  short8 a1[2];
  #pragma unroll
  for (int f = 0; f < 2; ++f){
    const float* w = WO + WO_W1 + (q * 16 + nlo) * 64 + f * 32 + quad * 8;
    short8 a;
    #pragma unroll
    for (int j = 0; j < 8; ++j) a[j] = (short)f2bf(w[j]);
    a1[f] = a;
  }
  float4v b1v = *(const float4v*)(WO + WO_B1 + q * 16 + quad * 4);
  #pragma unroll
  for (int nt = 0; nt < 4; ++nt){
    const int hb = (nt * 16 + nlo) * 72 + quad * 8;
    float4v a = b1v;
    a = MFMA16(a1[0], *(const short8*)&hHi[hb], a);
    a = MFMA16(a1[1], *(const short8*)&hHi[hb + 32], a);
    a = MFMA16(a1[0], *(const short8*)&hLo[hb], a);
    a = MFMA16(a1[1], *(const short8*)&hLo[hb + 32], a);
    float4v rv;
    #pragma unroll
    for (int r = 0; r < 4; ++r) rv[r] = fmaxf(a[r], 0.0f);
    *(float4v*)&x1T[(nt * 16 + nlo) * 68 + q * 16 + quad * 4] = rv;
  }
  __syncthreads();

  const int bloc = threadIdx.x >> 2;
  const int r0 = threadIdx.x & 3;
  const float* w2 = WO + WO_W2;
  const float* b2 = WO + WO_B2;
  for (int r = r0; r < 9; r += 4){
    float acc = b2[r];
    const float* wr = w2 + r * 64;
    #pragma unroll
    for (int k = 0; k < 64; ++k) acc = fmaf(wr[k], x1T[bloc * 68 + k], acc);
    if (isbf) ((u16*)out)[(size_t)(b0 + bloc) * 9 + r] = f2bf(acc);
    else      ((float*)out)[(size_t)(b0 + bloc) * 9 + r] = acc;
  }
}

extern "C" void kernel_launch(void* const* d_in, const int* in_sizes, int n_in,
                              void* d_out, int out_size, void* d_ws, size_t ws_size,
                              hipStream_t stream){
  char* ws = (char*)d_ws;
  float* WF = (float*)ws;
  size_t off = ((size_t)WF_TOTAL * 4 + 255) & ~(size_t)255;
  u16* sTx = (u16*)(ws + off);    off += (size_t)3 * 64 * NB * 8 * 2;
  u16* xpartT = (u16*)(ws + off); off += (size_t)3 * NB * 128 * 2;
  int* nar = (int*)(ws + off);    off += (size_t)3 * NB * 4;
  int* flag = (int*)(ws + off);   off += 256;
  int* hist = (int*)(ws + off);   off += 3 * 65 * 4;
  int* cnt  = (int*)(ws + off);   off += 3 * 4;
  int* offs = (int*)(ws + off);   off += 3 * 65 * 4;
  int* idx  = (int*)(ws + off);   off += (size_t)3 * NB * 4;
  float* ztraj = (float*)(ws + off); off += 2 * 64 * 4;

  PtrTab P;
  for (int i = 0; i < 36; ++i) P.p[i] = d_in[i];

  SegTab S;
  int si = 0;
  for (int t = 0; t < 3; ++t){
    int base = 4 + 8 * t;
    int d = t * TW;
    S.s[si++] = { base + 2, -1,       d + W_WIH,  1536  };
    S.s[si++] = { base + 3, -1,       d + W_WHH,  16384 };
    S.s[si++] = { base + 4, base + 5, d + W_BSUM, 256   };
    S.s[si++] = { base + 6, -1,       d + W_WTS,  4096  };
    S.s[si++] = { base + 7, -1,       d + W_BTS,  64    };
    S.s[si++] = { base + 0, -1,       d + W_WOS,  448   };
    S.s[si++] = { base + 1, -1,       d + W_BOS,  64    };
  }
  {
    int O = W_OUT;
    S.s[si++] = { 28, -1, O + WO_WIHO, 32768 };
    S.s[si++] = { 29, -1, O + WO_WHHO, 16384 };
    S.s[si++] = { 30, 31, O + WO_BSUM, 256   };
    S.s[si++] = { 32, -1, O + WO_W1,   4096  };
    S.s[si++] = { 33, -1, O + WO_B1,   64    };
    S.s[si++] = { 34, -1, O + WO_W2,   576   };
    S.s[si++] = { 35, -1, O + WO_B2,   9     };
  }

  const int* hl_ptr = (const int*)d_in[3];

  kdetect<<<dim3(1), 64, 0, stream>>>(d_in[7], flag);
  kweights<<<dim3(28), 256, 0, stream>>>(P, S, WF, flag);
  kprep<<<dim3(NB / 256, 3), 256, 0, stream>>>(d_in[0], d_in[1], hl_ptr, WF, sTx, nar, xpartT, flag);
  hipMemsetAsync(hist, 0, (3 * 65 + 3) * 4, stream);
  khist<<<dim3(NB / 256, 3), 256, 0, stream>>>(hl_ptr, nar, hist);
  kscan<<<dim3(1), 64, 0, stream>>>(hist, offs, cnt);
  kscatter<<<dim3(NB / 256, 3), 256, 0, stream>>>(hl_ptr, nar, offs, idx);
  kpad<<<dim3(3), 64, 0, stream>>>(cnt, idx);
  kmainM<<<dim3(129, 3), 256, 0, stream>>>(nar, WF, sTx, xpartT, idx, cnt, ztraj);
  kbcast<<<dim3(NB / 256), 256, 0, stream>>>(hl_ptr, ztraj, xpartT);
  kfinalM<<<dim3(NB / 64), 256, 0, stream>>>(WF, xpartT, hl_ptr, d_out, flag);
}

// Round 10
// 453.447 us; speedup vs baseline: 10.8238x; 1.3710x over previous
//
#include <hip/hip_runtime.h>
#include <hip/hip_bf16.h>

#define NB 8192
#define SROW 391

// ---- weight ws layout (floats) ----
#define TW      22848
#define W_WIH   0
#define W_WHH   1536
#define W_BSUM  17920
#define W_WTS   18176
#define W_BTS   22272
#define W_WOS   22336
#define W_BOS   22784
#define W_OUT   68544
#define WO_WIHO 0
#define WO_WHHO 32768
#define WO_BSUM 49152
#define WO_W1   49408
#define WO_B1   53504
#define WO_W2   53568
#define WO_B2   54144
#define WF_TOTAL 122697

typedef unsigned short u16;
typedef __attribute__((ext_vector_type(8))) short short8;
typedef __attribute__((ext_vector_type(4))) float float4v;

#define MFMA16(a, b, c) __builtin_amdgcn_mfma_f32_16x16x32_bf16((a), (b), (c), 0, 0, 0)

__device__ __forceinline__ float bf2f(u16 u){ return __uint_as_float(((unsigned)u) << 16); }
__device__ __forceinline__ u16 f2bf(float f){
  unsigned x = __float_as_uint(f);
  unsigned r = (x + 0x7FFFu + ((x >> 16) & 1u)) >> 16;   // RNE
  return (u16)r;
}
__device__ __forceinline__ bool isnanf32(float f){
  unsigned x = __float_as_uint(f);
  return (x & 0x7FFFFFFFu) > 0x7F800000u;
}
__device__ __forceinline__ float ldin(const void* p, size_t i, bool isbf){
  if (isbf) return bf2f(((const u16*)p)[i]);
  return ((const float*)p)[i];
}
__device__ __forceinline__ float sigm(float x){ return __fdividef(1.0f, 1.0f + __expf(-x)); }
__device__ __forceinline__ float tanh_f(float x){ return __fdividef(2.0f, 1.0f + __expf(-2.0f * x)) - 1.0f; }

// wave-wide dtype detect from Whh0 bit patterns (bf16 exponents cluster; f32 low-halves don't)
__device__ __forceinline__ bool detect_bf(const void* whh0){
  const u16* u = (const u16*)whh0;
  const int l = threadIdx.x & 63;
  int e = (u[2 * l] >> 7) & 0xFF;
  unsigned long long m = __ballot(e >= 100 && e <= 141);
  return __popcll(m) >= 32;
}

struct Seg { int src; int src2; int dst; int n; };
struct SegTab { Seg s[28]; };
struct PtrTab { const void* p[36]; };

// ---------- kernel W: convert weights -> fp32 into ws; also publishes dtype flag ----------
__global__ __launch_bounds__(256) void kweights(PtrTab P, SegTab S, float* __restrict__ WF,
                                                const void* __restrict__ whh0, int* __restrict__ flag){
  const bool isbf = detect_bf(whh0);
  if (blockIdx.x == 0 && threadIdx.x == 0) *flag = isbf ? 1 : 0;
  Seg sg = S.s[blockIdx.x];
  const void* a = P.p[sg.src];
  const void* b = (sg.src2 >= 0) ? P.p[sg.src2] : nullptr;
  for (int i = threadIdx.x; i < sg.n; i += 256){
    float v = ldin(a, i, isbf);
    if (b) v += ldin(b, i, isbf);
    WF[sg.dst + i] = v;
  }
}

// ---------- kernel P: wave-per-batch coalesced prep. sTx layout [t][b][step][8] ----------
__global__ __launch_bounds__(256) void kprep(const void* __restrict__ s,
                                             const void* __restrict__ sh,
                                             const int* __restrict__ hist_len,
                                             const float* __restrict__ WF,
                                             u16* __restrict__ sTx,
                                             int* __restrict__ nar,
                                             u16* __restrict__ xpartT,
                                             const int* __restrict__ flag){
  __shared__ u16 stage[4][400];
  const bool isbf = (*flag != 0);
  const int t = blockIdx.y;
  const int w = threadIdx.x >> 6;
  const int l = threadIdx.x & 63;
  const int b = blockIdx.x * 4 + w;
  const int hl = hist_len[b];

  const void* base; size_t soff;
  if (t == 0){ base = s; soff = (size_t)b * SROW; }
  else {
    if (hl < 2) return;   // zero-input case handled via zxp in kfinalM (wave-uniform exit)
    base = sh; soff = ((size_t)b * 2 + ((t == 1) ? 1 : 0)) * SROW;
  }

  // coalesced row load: 7 chunks of 64
  float val[7];
  #pragma unroll
  for (int k = 0; k < 7; ++k){
    const int e = k * 64 + l;
    float v = 0.0f;
    if (e < SROW) v = isbf ? bf2f(((const u16*)base)[soff + e]) : ((const float*)base)[soff + e];
    val[k] = v;
  }
  // sOS (fp32, exact) from chunk-0 lanes 0..6
  float sOS[7];
  #pragma unroll
  for (int i = 0; i < 7; ++i) sOS[i] = __shfl(val[0], i);

  // n = count of non-NaN first-features (positions e = 7+6r)
  int n = 0;
  #pragma unroll
  for (int k = 0; k < 7; ++k){
    const int e = k * 64 + l;
    const bool firstf = (e >= 7) && (e < SROW) && ((e - 7) % 6 == 0);
    unsigned long long m = __ballot(firstf && !isnanf32(val[k]));
    n += __popcll(m);
  }

  // stage TS features (NaN->0, bf16)
  #pragma unroll
  for (int k = 0; k < 7; ++k){
    const int e = k * 64 + l;
    if (e >= 7 && e < SROW) stage[w][e] = f2bf(isnanf32(val[k]) ? 0.0f : val[k]);
  }
  // wave-private LDS: compiler inserts lgkmcnt before dependent reads

  // lane r packs row r -> contiguous 16B write per lane (1KB/batch)
  {
    const int r = l;
    u16 v0 = stage[w][7 + 6 * r],  v1 = stage[w][8 + 6 * r],  v2 = stage[w][9 + 6 * r];
    u16 v3 = stage[w][10 + 6 * r], v4 = stage[w][11 + 6 * r], v5 = stage[w][12 + 6 * r];
    uint4 wv;
    wv.x = (uint)v0 | ((uint)v1 << 16);
    wv.y = (uint)v2 | ((uint)v3 << 16);
    wv.z = (uint)v4 | ((uint)v5 << 16);
    wv.w = 0u;
    *(uint4*)&sTx[((size_t)(t * NB + b) * 64 + r) * 8] = wv;
  }
  if (l == 0) nar[t * NB + b] = n;

  // xOS = relu(WOS @ sOS + bOS): lane = unit
  const float* wos = WF + t * TW + W_WOS;
  const float* bos = WF + t * TW + W_BOS;
  float acc = bos[l];
  #pragma unroll
  for (int i = 0; i < 7; ++i) acc = fmaf(wos[l * 7 + i], sOS[i], acc);
  xpartT[((size_t)(t * NB + b)) * 128 + l] = f2bf(fmaxf(acc, 0.0f));
}

// ---------- kernel S: fused counting sort by n (ascending) + compaction + pad to 32 ----------
__global__ __launch_bounds__(256) void ksort(const int* __restrict__ hist_len,
                                             const int* __restrict__ nar,
                                             int* __restrict__ idx, int* __restrict__ cnt){
  __shared__ int h[65];
  __shared__ int o[66];
  const int t = blockIdx.x;
  for (int i = threadIdx.x; i < 65; i += 256) h[i] = 0;
  __syncthreads();
  for (int b = threadIdx.x; b < NB; b += 256){
    if (t > 0 && hist_len[b] < 2) continue;
    int key = min(max(nar[t * NB + b], 0), 64);
    atomicAdd(&h[key], 1);
  }
  __syncthreads();
  if (threadIdx.x == 0){
    int acc = 0;
    for (int k = 0; k < 65; ++k){ o[k] = acc; acc += h[k]; }
    o[65] = acc;
    cnt[t] = acc;
  }
  __syncthreads();
  for (int b = threadIdx.x; b < NB; b += 256){
    if (t > 0 && hist_len[b] < 2) continue;
    int key = min(max(nar[t * NB + b], 0), 64);
    int pos = atomicAdd(&o[key], 1);
    idx[t * NB + pos] = b;
  }
  __syncthreads();
  const int c = o[65];
  if (c > 0){
    const int pad = (c + 31) & ~31;
    const int last = idx[t * NB + c - 1];
    for (int i = c + threadIdx.x; i < pad; i += 256) idx[t * NB + i] = last;
  }
}

// ---------- kernel M: inner LSTM via MFMA, 32-batch tiles (per-batch math identical to r9) ----------
__global__ __launch_bounds__(256) void kmainM(const int* __restrict__ nar,
                                              const float* __restrict__ WF,
                                              const u16* __restrict__ sTx,
                                              u16* __restrict__ xpartT,
                                              const int* __restrict__ idx,
                                              const int* __restrict__ cnt,
                                              u16* __restrict__ zxp){
  __shared__ u16 hHi[2][32 * 72];
  __shared__ u16 hLo[2][32 * 72];
  __shared__ float zh[64];
  __shared__ float zg[256];
  const int t = blockIdx.y;
  const float* Wt = WF + t * TW;

  // ---- special block: zero-input trajectory + zxp (t=1,2) ----
  if (blockIdx.x == 256){
    if (t == 0) return;
    const int u = threadIdx.x & 63;
    const int w = threadIdx.x >> 6;
    const int row = w * 64 + u;
    const float* wr = Wt + W_WHH + row * 64;
    const float bsu = Wt[W_BSUM + row];
    if (w == 0) zh[u] = 0.0f;
    float zc = 0.0f;
    __syncthreads();
    for (int step = 0; step < 64; ++step){
      float a0 = 0.0f, a1 = 0.0f, a2 = 0.0f, a3 = 0.0f;
      #pragma unroll
      for (int k = 0; k < 64; k += 4){
        a0 = fmaf(wr[k],     zh[k],     a0);
        a1 = fmaf(wr[k + 1], zh[k + 1], a1);
        a2 = fmaf(wr[k + 2], zh[k + 2], a2);
        a3 = fmaf(wr[k + 3], zh[k + 3], a3);
      }
      zg[row] = bsu + (a0 + a1) + (a2 + a3);
      __syncthreads();
      if (w == 0){
        float gi = zg[u], gf = zg[64 + u], gg = zg[128 + u], go = zg[192 + u];
        zc = sigm(gf) * zc + sigm(gi) * tanh_f(gg);
        zh[u] = sigm(go) * tanh_f(zc);
      }
      __syncthreads();
    }
    if (w == 0){
      float acc = Wt[W_BTS + u];
      const float* wts = Wt + W_WTS + u * 64;
      for (int k = 0; k < 64; ++k) acc = fmaf(wts[k], zh[k], acc);
      zxp[(t - 1) * 128 + 64 + u] = f2bf(fmaxf(acc, 0.0f));               // xTS (zero input)
      zxp[(t - 1) * 128 + u]      = f2bf(fmaxf(Wt[W_BOS + u], 0.0f));     // xOS (sOS = 0)
    }
    return;
  }

  const int c = cnt[t];
  if (blockIdx.x * 32 >= c) return;

  const int lane = threadIdx.x & 63;
  const int q    = __builtin_amdgcn_readfirstlane((int)(threadIdx.x >> 6));
  const int nlo  = lane & 15;
  const int quad = lane >> 4;

  for (int i = threadIdx.x; i < 32 * 72; i += 256){ hHi[0][i] = 0; hLo[0][i] = 0; }

  // A-fragments (resident)
  short8 aW[4][2], aX[4];
  float4v binit[4];
  #pragma unroll
  for (int g = 0; g < 4; ++g){
    const int mrow = g * 64 + q * 16 + nlo;
    const float* wr = Wt + W_WHH + mrow * 64;
    #pragma unroll
    for (int f = 0; f < 2; ++f){
      const int k0 = f * 32 + quad * 8;
      short8 a;
      #pragma unroll
      for (int j = 0; j < 8; ++j) a[j] = (short)f2bf(wr[k0 + j]);
      aW[g][f] = a;
    }
    const float* wi = Wt + W_WIH + mrow * 6;
    short8 ax = {0, 0, 0, 0, 0, 0, 0, 0};
    if (quad == 0){
      #pragma unroll
      for (int j = 0; j < 6; ++j) ax[j] = (short)f2bf(wi[j]);
    }
    aX[g] = ax;
    binit[g] = *(const float4v*)(Wt + W_BSUM + g * 64 + q * 16 + quad * 4);
  }

  int bb2[2], n2[2];
  const u16* sB[2];
  #pragma unroll
  for (int nt = 0; nt < 2; ++nt){
    bb2[nt] = idx[t * NB + blockIdx.x * 32 + nt * 16 + nlo];
    n2[nt]  = nar[t * NB + bb2[nt]];
    sB[nt]  = sTx + (size_t)(t * NB + bb2[nt]) * 512;   // [b][step][8] u16
  }
  int nmax = max(n2[0], n2[1]);
  #pragma unroll
  for (int o = 1; o < 16; o <<= 1) nmax = max(nmax, __shfl_xor(nmax, o));

  float c_st[2][4], h_st[2][4];
  #pragma unroll
  for (int nt = 0; nt < 2; ++nt)
    #pragma unroll
    for (int r = 0; r < 4; ++r){ c_st[nt][r] = 0.0f; h_st[nt][r] = 0.0f; }

  // prefetch step-0 x fragments
  short8 xcur[2], xnxt[2];
  #pragma unroll
  for (int nt = 0; nt < 2; ++nt){
    short8 xf = {0, 0, 0, 0, 0, 0, 0, 0};
    if (lane < 16) xf = *(const short8*)sB[nt];
    xcur[nt] = xf;
  }

  __syncthreads();

  for (int step = 0; step < nmax; ++step){
    const int ns = min(step + 1, 63);
    #pragma unroll
    for (int nt = 0; nt < 2; ++nt){
      short8 xf = {0, 0, 0, 0, 0, 0, 0, 0};
      if (lane < 16) xf = *(const short8*)(sB[nt] + (size_t)ns * 8);
      xnxt[nt] = xf;
    }

    const u16* rHi = hHi[step & 1];
    const u16* rLo = hLo[step & 1];
    u16* wHi = hHi[(step + 1) & 1];
    u16* wLo = hLo[(step + 1) & 1];
    float4v acc[4][2];
    #pragma unroll
    for (int nt = 0; nt < 2; ++nt){
      const int hb = (nt * 16 + nlo) * 72 + quad * 8;
      short8 h0 = *(const short8*)&rHi[hb];
      short8 h1 = *(const short8*)&rHi[hb + 32];
      short8 l0 = *(const short8*)&rLo[hb];
      short8 l1 = *(const short8*)&rLo[hb + 32];
      #pragma unroll
      for (int g = 0; g < 4; ++g){
        float4v a = binit[g];
        a = MFMA16(aX[g], xcur[nt], a);     // r9 order: x first
        a = MFMA16(aW[g][0], h0, a);
        a = MFMA16(aW[g][1], h1, a);
        a = MFMA16(aW[g][0], l0, a);
        a = MFMA16(aW[g][1], l1, a);
        acc[g][nt] = a;
      }
    }
    #pragma unroll
    for (int nt = 0; nt < 2; ++nt){
      const bool v = (step < n2[nt]);
      u16 hb4[4], lb4[4];
      #pragma unroll
      for (int r = 0; r < 4; ++r){
        float gi = acc[0][nt][r], gf = acc[1][nt][r], gg = acc[2][nt][r], go = acc[3][nt][r];
        float cn = sigm(gf) * c_st[nt][r] + sigm(gi) * tanh_f(gg);
        float hn = sigm(go) * tanh_f(cn);
        c_st[nt][r] = v ? cn : c_st[nt][r];
        h_st[nt][r] = v ? hn : h_st[nt][r];
        u16 hi = f2bf(h_st[nt][r]);
        float lo = h_st[nt][r] - bf2f(hi);
        hb4[r] = hi; lb4[r] = f2bf(lo);
      }
      const int off = (nt * 16 + nlo) * 72 + q * 16 + quad * 4;
      uint2 hw, lw;
      hw.x = (uint)hb4[0] | ((uint)hb4[1] << 16);
      hw.y = (uint)hb4[2] | ((uint)hb4[3] << 16);
      lw.x = (uint)lb4[0] | ((uint)lb4[1] << 16);
      lw.y = (uint)lb4[2] | ((uint)lb4[3] << 16);
      *(uint2*)&wHi[off] = hw;
      *(uint2*)&wLo[off] = lw;
    }
    #pragma unroll
    for (int nt = 0; nt < 2; ++nt) xcur[nt] = xnxt[nt];
    __syncthreads();
  }

  // xTS epilogue from final h buffer
  const u16* fHi = hHi[nmax & 1];
  const u16* fLo = hLo[nmax & 1];
  short8 aT[2];
  #pragma unroll
  for (int f = 0; f < 2; ++f){
    const float* wr = Wt + W_WTS + (q * 16 + nlo) * 64 + f * 32 + quad * 8;
    short8 a;
    #pragma unroll
    for (int j = 0; j < 8; ++j) a[j] = (short)f2bf(wr[j]);
    aT[f] = a;
  }
  float4v btsv = *(const float4v*)(Wt + W_BTS + q * 16 + quad * 4);
  #pragma unroll
  for (int nt = 0; nt < 2; ++nt){
    const int hb = (nt * 16 + nlo) * 72 + quad * 8;
    float4v a = btsv;
    a = MFMA16(aT[0], *(const short8*)&fHi[hb], a);
    a = MFMA16(aT[1], *(const short8*)&fHi[hb + 32], a);
    a = MFMA16(aT[0], *(const short8*)&fLo[hb], a);
    a = MFMA16(aT[1], *(const short8*)&fLo[hb + 32], a);
    u16 o4[4];
    #pragma unroll
    for (int r = 0; r < 4; ++r) o4[r] = f2bf(fmaxf(a[r], 0.0f));
    size_t oidx = ((size_t)(t * NB + bb2[nt])) * 128 + 64 + q * 16 + quad * 4;
    uint2 w;
    w.x = (uint)o4[0] | ((uint)o4[1] << 16);
    w.y = (uint)o4[2] | ((uint)o4[3] << 16);
    *(uint2*)&xpartT[oidx] = w;
  }
}

// ---------- kernel F: outer LSTM via MFMA (3 steps) + MLP; zxp fold-in for hl<2 ----------
__global__ __launch_bounds__(256) void kfinalM(const float* __restrict__ WF,
                                               const u16* __restrict__ xpartT,
                                               const u16* __restrict__ zxp,
                                               const int* __restrict__ hist_len,
                                               void* __restrict__ out,
                                               const int* __restrict__ flag){
  __shared__ u16 hHi[64 * 72];
  __shared__ u16 hLo[64 * 72];
  __shared__ float x1T[64 * 68];
  const bool isbf = (*flag != 0);
  const int b0   = blockIdx.x * 64;
  const int lane = threadIdx.x & 63;
  const int q    = __builtin_amdgcn_readfirstlane((int)(threadIdx.x >> 6));
  const int nlo  = lane & 15;
  const int quad = lane >> 4;

  for (int i = threadIdx.x; i < 64 * 72; i += 256){ hHi[i] = 0; hLo[i] = 0; }

  const float* WO = WF + W_OUT;
  int hl4[4];
  #pragma unroll
  for (int nt = 0; nt < 4; ++nt) hl4[nt] = hist_len[b0 + nt * 16 + nlo];

  short8 aI[4][4], aH[4][2];
  float4v bi4[4];
  #pragma unroll
  for (int g = 0; g < 4; ++g){
    const int mrow = g * 64 + q * 16 + nlo;
    #pragma unroll
    for (int f = 0; f < 4; ++f){
      const float* w = WO + WO_WIHO + mrow * 128 + f * 32 + quad * 8;
      short8 a;
      #pragma unroll
      for (int j = 0; j < 8; ++j) a[j] = (short)f2bf(w[j]);
      aI[g][f] = a;
    }
    #pragma unroll
    for (int f = 0; f < 2; ++f){
      const float* w = WO + WO_WHHO + mrow * 64 + f * 32 + quad * 8;
      short8 a;
      #pragma unroll
      for (int j = 0; j < 8; ++j) a[j] = (short)f2bf(w[j]);
      aH[g][f] = a;
    }
    bi4[g] = *(const float4v*)(WO + WO_BSUM + g * 64 + q * 16 + quad * 4);
  }

  float c_st[4][4], h_st[4][4];
  #pragma unroll
  for (int nt = 0; nt < 4; ++nt)
    #pragma unroll
    for (int r = 0; r < 4; ++r){ c_st[nt][r] = 0.0f; h_st[nt][r] = 0.0f; }
  __syncthreads();

  for (int p = 0; p < 3; ++p){
    float4v acc[4][4];
    #pragma unroll
    for (int nt = 0; nt < 4; ++nt){
      const int bb = b0 + nt * 16 + nlo;
      const int tt = 2 - ((p - hl4[nt] + 2) % 3);
      const u16* xb = (tt > 0 && hl4[nt] < 2) ? (zxp + (tt - 1) * 128)
                                              : xpartT + ((size_t)(tt * NB + bb)) * 128;
      short8 xf[4];
      #pragma unroll
      for (int f = 0; f < 4; ++f) xf[f] = *(const short8*)(xb + f * 32 + quad * 8);
      const int hb = (nt * 16 + nlo) * 72 + quad * 8;
      short8 h0 = *(const short8*)&hHi[hb];
      short8 h1 = *(const short8*)&hHi[hb + 32];
      short8 l0 = *(const short8*)&hLo[hb];
      short8 l1 = *(const short8*)&hLo[hb + 32];
      #pragma unroll
      for (int g = 0; g < 4; ++g){
        float4v a = bi4[g];
        #pragma unroll
        for (int f = 0; f < 4; ++f) a = MFMA16(aI[g][f], xf[f], a);
        a = MFMA16(aH[g][0], h0, a);
        a = MFMA16(aH[g][1], h1, a);
        a = MFMA16(aH[g][0], l0, a);
        a = MFMA16(aH[g][1], l1, a);
        acc[g][nt] = a;
      }
    }
    __syncthreads();
    #pragma unroll
    for (int nt = 0; nt < 4; ++nt){
      const bool v = (p <= hl4[nt]);
      u16 hb4[4], lb4[4];
      #pragma unroll
      for (int r = 0; r < 4; ++r){
        float gi = acc[0][nt][r], gf = acc[1][nt][r], gg = acc[2][nt][r], go = acc[3][nt][r];
        float cn = sigm(gf) * c_st[nt][r] + sigm(gi) * tanh_f(gg);
        float hn = sigm(go) * tanh_f(cn);
        c_st[nt][r] = v ? cn : c_st[nt][r];
        h_st[nt][r] = v ? hn : h_st[nt][r];
        u16 hi = f2bf(h_st[nt][r]);
        float lo = h_st[nt][r] - bf2f(hi);
        hb4[r] = hi; lb4[r] = f2bf(lo);
      }
      const int off = (nt * 16 + nlo) * 72 + q * 16 + quad * 4;
      uint2 hw, lw;
      hw.x = (uint)hb4[0] | ((uint)hb4[1] << 16);
      hw.y = (uint)hb4[2] | ((uint)hb4[3] << 16);
      lw.x = (uint)lb4[0] | ((uint)lb4[1] << 16);
      lw.y = (uint)lb4[2] | ((uint)lb4[3] << 16);
      *(uint2*)&hHi[off] = hw;
      *(uint2*)&hLo[off] = lw;
    }
    __syncthreads();
  }

  short8 a1[2];
  #pragma unroll
  for (int f = 0; f < 2; ++f){
    const float* w = WO + WO_W1 + (q * 16 + nlo) * 64 + f * 32 + quad * 8;
    short8 a;
    #pragma unroll
    for (int j = 0; j < 8; ++j) a[j] = (short)f2bf(w[j]);
    a1[f] = a;
  }
  float4v b1v = *(const float4v*)(WO + WO_B1 + q * 16 + quad * 4);
  #pragma unroll
  for (int nt = 0; nt < 4; ++nt){
    const int hb = (nt * 16 + nlo) * 72 + quad * 8;
    float4v a = b1v;
    a = MFMA16(a1[0], *(const short8*)&hHi[hb], a);
    a = MFMA16(a1[1], *(const short8*)&hHi[hb + 32], a);
    a = MFMA16(a1[0], *(const short8*)&hLo[hb], a);
    a = MFMA16(a1[1], *(const short8*)&hLo[hb + 32], a);
    float4v rv;
    #pragma unroll
    for (int r = 0; r < 4; ++r) rv[r] = fmaxf(a[r], 0.0f);
    *(float4v*)&x1T[(nt * 16 + nlo) * 68 + q * 16 + quad * 4] = rv;
  }
  __syncthreads();

  const int bloc = threadIdx.x >> 2;
  const int r0 = threadIdx.x & 3;
  const float* w2 = WO + WO_W2;
  const float* b2 = WO + WO_B2;
  for (int r = r0; r < 9; r += 4){
    float acc = b2[r];
    const float* wr = w2 + r * 64;
    #pragma unroll
    for (int k = 0; k < 64; ++k) acc = fmaf(wr[k], x1T[bloc * 68 + k], acc);
    if (isbf) ((u16*)out)[(size_t)(b0 + bloc) * 9 + r] = f2bf(acc);
    else      ((float*)out)[(size_t)(b0 + bloc) * 9 + r] = acc;
  }
}

extern "C" void kernel_launch(void* const* d_in, const int* in_sizes, int n_in,
                              void* d_out, int out_size, void* d_ws, size_t ws_size,
                              hipStream_t stream){
  char* ws = (char*)d_ws;
  float* WF = (float*)ws;
  size_t off = ((size_t)WF_TOTAL * 4 + 255) & ~(size_t)255;
  u16* sTx = (u16*)(ws + off);    off += (size_t)3 * NB * 512 * 2;      // [t][b][step][8]
  u16* xpartT = (u16*)(ws + off); off += (size_t)3 * NB * 128 * 2;
  int* nar = (int*)(ws + off);    off += (size_t)3 * NB * 4;
  int* flag = (int*)(ws + off);   off += 256;
  int* cnt  = (int*)(ws + off);   off += 256;
  int* idx  = (int*)(ws + off);   off += (size_t)3 * NB * 4;
  u16* zxp  = (u16*)(ws + off);   off += 2 * 128 * 2;

  PtrTab P;
  for (int i = 0; i < 36; ++i) P.p[i] = d_in[i];

  SegTab S;
  int si = 0;
  for (int t = 0; t < 3; ++t){
    int base = 4 + 8 * t;
    int d = t * TW;
    S.s[si++] = { base + 2, -1,       d + W_WIH,  1536  };
    S.s[si++] = { base + 3, -1,       d + W_WHH,  16384 };
    S.s[si++] = { base + 4, base + 5, d + W_BSUM, 256   };
    S.s[si++] = { base + 6, -1,       d + W_WTS,  4096  };
    S.s[si++] = { base + 7, -1,       d + W_BTS,  64    };
    S.s[si++] = { base + 0, -1,       d + W_WOS,  448   };
    S.s[si++] = { base + 1, -1,       d + W_BOS,  64    };
  }
  {
    int O = W_OUT;
    S.s[si++] = { 28, -1, O + WO_WIHO, 32768 };
    S.s[si++] = { 29, -1, O + WO_WHHO, 16384 };
    S.s[si++] = { 30, 31, O + WO_BSUM, 256   };
    S.s[si++] = { 32, -1, O + WO_W1,   4096  };
    S.s[si++] = { 33, -1, O + WO_B1,   64    };
    S.s[si++] = { 34, -1, O + WO_W2,   576   };
    S.s[si++] = { 35, -1, O + WO_B2,   9     };
  }

  const int* hl_ptr = (const int*)d_in[3];

  kweights<<<dim3(28), 256, 0, stream>>>(P, S, WF, d_in[7], flag);
  kprep<<<dim3(NB / 4, 3), 256, 0, stream>>>(d_in[0], d_in[1], hl_ptr, WF, sTx, nar, xpartT, flag);
  ksort<<<dim3(3), 256, 0, stream>>>(hl_ptr, nar, idx, cnt);
  kmainM<<<dim3(257, 3), 256, 0, stream>>>(nar, WF, sTx, xpartT, idx, cnt, zxp);
  kfinalM<<<dim3(NB / 64), 256, 0, stream>>>(WF, xpartT, zxp, hl_ptr, d_out, flag);
}

// Round 11
// 409.256 us; speedup vs baseline: 11.9926x; 1.1080x over previous
//
#include <hip/hip_runtime.h>
#include <hip/hip_bf16.h>

#define NB 8192
#define SROW 391

// ---- weight ws layout (floats) ----
#define TW      22848
#define W_WIH   0
#define W_WHH   1536
#define W_BSUM  17920
#define W_WTS   18176
#define W_BTS   22272
#define W_WOS   22336
#define W_BOS   22784
#define W_OUT   68544
#define WO_WIHO 0
#define WO_WHHO 32768
#define WO_BSUM 49152
#define WO_W1   49408
#define WO_B1   53504
#define WO_W2   53568
#define WO_B2   54144
#define WF_TOTAL 122697

typedef unsigned short u16;
typedef __attribute__((ext_vector_type(8))) short short8;
typedef __attribute__((ext_vector_type(4))) float float4v;

#define MFMA16(a, b, c) __builtin_amdgcn_mfma_f32_16x16x32_bf16((a), (b), (c), 0, 0, 0)

__device__ __forceinline__ float bf2f(u16 u){ return __uint_as_float(((unsigned)u) << 16); }
__device__ __forceinline__ u16 f2bf(float f){
  unsigned x = __float_as_uint(f);
  unsigned r = (x + 0x7FFFu + ((x >> 16) & 1u)) >> 16;   // RNE
  return (u16)r;
}
__device__ __forceinline__ bool isnanf32(float f){
  unsigned x = __float_as_uint(f);
  return (x & 0x7FFFFFFFu) > 0x7F800000u;
}
__device__ __forceinline__ float ldin(const void* p, size_t i, bool isbf){
  if (isbf) return bf2f(((const u16*)p)[i]);
  return ((const float*)p)[i];
}
__device__ __forceinline__ float sigm(float x){ return __fdividef(1.0f, 1.0f + __expf(-x)); }
__device__ __forceinline__ float tanh_f(float x){ return __fdividef(2.0f, 1.0f + __expf(-2.0f * x)) - 1.0f; }

__device__ __forceinline__ bool detect_bf(const void* whh0){
  const u16* u = (const u16*)whh0;
  const int l = threadIdx.x & 63;
  int e = (u[2 * l] >> 7) & 0xFF;
  unsigned long long m = __ballot(e >= 100 && e <= 141);
  return __popcll(m) >= 32;
}

struct Seg { int src; int src2; int soff; int dst; int n; };
struct SegTab { Seg s[35]; };
struct PtrTab { const void* p[36]; };

// ---------- kernel W: weights -> fp32; publish dtype flag; zero histogram ----------
__global__ __launch_bounds__(256) void kweights(PtrTab P, SegTab S, float* __restrict__ WF,
                                                const void* __restrict__ whh0, int* __restrict__ flag,
                                                int* __restrict__ ghist){
  const bool isbf = detect_bf(whh0);
  if (blockIdx.x == 0){
    if (threadIdx.x == 0) *flag = isbf ? 1 : 0;
    if (threadIdx.x < 195) ghist[threadIdx.x] = 0;
  }
  Seg sg = S.s[blockIdx.x];
  const void* a = P.p[sg.src];
  const void* b = (sg.src2 >= 0) ? P.p[sg.src2] : nullptr;
  for (int i = threadIdx.x; i < sg.n; i += 256){
    float v = ldin(a, sg.soff + i, isbf);
    if (b) v += ldin(b, sg.soff + i, isbf);
    WF[sg.dst + i] = v;
  }
}

// ---------- kernel P: wave-per-batch coalesced prep. sTx layout [t][b][step][8] ----------
__global__ __launch_bounds__(256) void kprep(const void* __restrict__ s,
                                             const void* __restrict__ sh,
                                             const int* __restrict__ hist_len,
                                             const float* __restrict__ WF,
                                             u16* __restrict__ sTx,
                                             int* __restrict__ nar,
                                             u16* __restrict__ xpartT,
                                             const int* __restrict__ flag){
  __shared__ u16 stage[4][400];
  const bool isbf = (*flag != 0);
  const int t = blockIdx.y;
  const int w = threadIdx.x >> 6;
  const int l = threadIdx.x & 63;
  const int b = blockIdx.x * 4 + w;
  const int hl = hist_len[b];

  const void* base; size_t soff;
  if (t == 0){ base = s; soff = (size_t)b * SROW; }
  else {
    if (hl < 2) return;   // zero-input case via zxp in kfinalM (wave-uniform exit)
    base = sh; soff = ((size_t)b * 2 + ((t == 1) ? 1 : 0)) * SROW;
  }

  float val[7];
  #pragma unroll
  for (int k = 0; k < 7; ++k){
    const int e = k * 64 + l;
    float v = 0.0f;
    if (e < SROW) v = isbf ? bf2f(((const u16*)base)[soff + e]) : ((const float*)base)[soff + e];
    val[k] = v;
  }
  float sOS[7];
  #pragma unroll
  for (int i = 0; i < 7; ++i) sOS[i] = __shfl(val[0], i);

  int n = 0;
  #pragma unroll
  for (int k = 0; k < 7; ++k){
    const int e = k * 64 + l;
    const bool firstf = (e >= 7) && (e < SROW) && ((e - 7) % 6 == 0);
    unsigned long long m = __ballot(firstf && !isnanf32(val[k]));
    n += __popcll(m);
  }

  #pragma unroll
  for (int k = 0; k < 7; ++k){
    const int e = k * 64 + l;
    if (e >= 7 && e < SROW) stage[w][e] = f2bf(isnanf32(val[k]) ? 0.0f : val[k]);
  }

  {
    const int r = l;
    u16 v0 = stage[w][7 + 6 * r],  v1 = stage[w][8 + 6 * r],  v2 = stage[w][9 + 6 * r];
    u16 v3 = stage[w][10 + 6 * r], v4 = stage[w][11 + 6 * r], v5 = stage[w][12 + 6 * r];
    uint4 wv;
    wv.x = (uint)v0 | ((uint)v1 << 16);
    wv.y = (uint)v2 | ((uint)v3 << 16);
    wv.z = (uint)v4 | ((uint)v5 << 16);
    wv.w = 0u;
    *(uint4*)&sTx[((size_t)(t * NB + b) * 64 + r) * 8] = wv;
  }
  if (l == 0) nar[t * NB + b] = n;

  const float* wos = WF + t * TW + W_WOS;
  const float* bos = WF + t * TW + W_BOS;
  float acc = bos[l];
  #pragma unroll
  for (int i = 0; i < 7; ++i) acc = fmaf(wos[l * 7 + i], sOS[i], acc);
  xpartT[((size_t)(t * NB + b)) * 128 + l] = f2bf(fmaxf(acc, 0.0f));
}

// ---------- sort (descending n = LPT schedule): hist -> scan -> scatter ----------
__global__ __launch_bounds__(256) void khistG(const int* __restrict__ hist_len,
                                              const int* __restrict__ nar,
                                              int* __restrict__ ghist){
  __shared__ int h[65];
  const int t = blockIdx.y;
  for (int i = threadIdx.x; i < 65; i += 256) h[i] = 0;
  __syncthreads();
  for (int i = threadIdx.x; i < 512; i += 256){
    const int b = blockIdx.x * 512 + i;
    if (t > 0 && hist_len[b] < 2) continue;
    int key = 64 - min(max(nar[t * NB + b], 0), 64);   // descending n
    atomicAdd(&h[key], 1);
  }
  __syncthreads();
  for (int k = threadIdx.x; k < 65; k += 256)
    if (h[k]) atomicAdd(&ghist[t * 65 + k], h[k]);
}
__global__ void kscanG(const int* __restrict__ ghist, int* __restrict__ offs, int* __restrict__ cnt){
  const int t = threadIdx.x;
  if (t >= 3) return;
  int acc = 0;
  for (int k = 0; k < 65; ++k){ offs[t * 65 + k] = acc; acc += ghist[t * 65 + k]; }
  cnt[t] = acc;
}
__global__ __launch_bounds__(256) void kscatG(const int* __restrict__ hist_len,
                                              const int* __restrict__ nar,
                                              int* __restrict__ offs, int* __restrict__ idx){
  const int t = blockIdx.y;
  for (int i = threadIdx.x; i < 512; i += 256){
    const int b = blockIdx.x * 512 + i;
    if (t > 0 && hist_len[b] < 2) continue;
    int key = 64 - min(max(nar[t * NB + b], 0), 64);
    int pos = atomicAdd(&offs[t * 65 + key], 1);
    idx[t * NB + pos] = b;
  }
}

// ---------- kernel M: inner LSTM via MFMA, 32-batch tiles, descending-n schedule ----------
__global__ __launch_bounds__(256) void kmainM(const int* __restrict__ nar,
                                              const float* __restrict__ WF,
                                              const u16* __restrict__ sTx,
                                              u16* __restrict__ xpartT,
                                              const int* __restrict__ idx,
                                              const int* __restrict__ cnt,
                                              u16* __restrict__ zxp){
  __shared__ u16 hHi[2][32 * 72];
  __shared__ u16 hLo[2][32 * 72];
  __shared__ float zh[64];
  __shared__ float zg[256];
  const int t = blockIdx.y;
  const float* Wt = WF + t * TW;

  // ---- block 0: zero-input trajectory + zxp (t=1,2); dispatched first ----
  if (blockIdx.x == 0){
    if (t == 0) return;
    const int u = threadIdx.x & 63;
    const int w = threadIdx.x >> 6;
    const int row = w * 64 + u;
    const float* wr = Wt + W_WHH + row * 64;
    const float bsu = Wt[W_BSUM + row];
    if (w == 0) zh[u] = 0.0f;
    float zc = 0.0f;
    __syncthreads();
    for (int step = 0; step < 64; ++step){
      float a0 = 0.0f, a1 = 0.0f, a2 = 0.0f, a3 = 0.0f;
      #pragma unroll
      for (int k = 0; k < 64; k += 4){
        a0 = fmaf(wr[k],     zh[k],     a0);
        a1 = fmaf(wr[k + 1], zh[k + 1], a1);
        a2 = fmaf(wr[k + 2], zh[k + 2], a2);
        a3 = fmaf(wr[k + 3], zh[k + 3], a3);
      }
      zg[row] = bsu + (a0 + a1) + (a2 + a3);
      __syncthreads();
      if (w == 0){
        float gi = zg[u], gf = zg[64 + u], gg = zg[128 + u], go = zg[192 + u];
        zc = sigm(gf) * zc + sigm(gi) * tanh_f(gg);
        zh[u] = sigm(go) * tanh_f(zc);
      }
      __syncthreads();
    }
    if (w == 0){
      float acc = Wt[W_BTS + u];
      const float* wts = Wt + W_WTS + u * 64;
      for (int k = 0; k < 64; ++k) acc = fmaf(wts[k], zh[k], acc);
      zxp[(t - 1) * 128 + 64 + u] = f2bf(fmaxf(acc, 0.0f));
      zxp[(t - 1) * 128 + u]      = f2bf(fmaxf(Wt[W_BOS + u], 0.0f));
    }
    return;
  }

  const int bx = blockIdx.x - 1;
  const int c = cnt[t];
  if (bx * 32 >= c) return;

  const int lane = threadIdx.x & 63;
  const int q    = __builtin_amdgcn_readfirstlane((int)(threadIdx.x >> 6));
  const int nlo  = lane & 15;
  const int quad = lane >> 4;

  for (int i = threadIdx.x; i < 32 * 72; i += 256){ hHi[0][i] = 0; hLo[0][i] = 0; }

  short8 aW[4][2], aX[4];
  float4v binit[4];
  #pragma unroll
  for (int g = 0; g < 4; ++g){
    const int mrow = g * 64 + q * 16 + nlo;
    const float* wr = Wt + W_WHH + mrow * 64;
    #pragma unroll
    for (int f = 0; f < 2; ++f){
      const int k0 = f * 32 + quad * 8;
      short8 a;
      #pragma unroll
      for (int j = 0; j < 8; ++j) a[j] = (short)f2bf(wr[k0 + j]);
      aW[g][f] = a;
    }
    const float* wi = Wt + W_WIH + mrow * 6;
    short8 ax = {0, 0, 0, 0, 0, 0, 0, 0};
    if (quad == 0){
      #pragma unroll
      for (int j = 0; j < 6; ++j) ax[j] = (short)f2bf(wi[j]);
    }
    aX[g] = ax;
    binit[g] = *(const float4v*)(Wt + W_BSUM + g * 64 + q * 16 + quad * 4);
  }

  int bb2[2], n2[2];
  const u16* sB[2];
  #pragma unroll
  for (int nt = 0; nt < 2; ++nt){
    const int pos = min(bx * 32 + nt * 16 + nlo, c - 1);   // clamp replaces pad
    bb2[nt] = idx[t * NB + pos];
    n2[nt]  = nar[t * NB + bb2[nt]];
    sB[nt]  = sTx + (size_t)(t * NB + bb2[nt]) * 512;
  }
  int nmax = max(n2[0], n2[1]);
  #pragma unroll
  for (int o = 1; o < 16; o <<= 1) nmax = max(nmax, __shfl_xor(nmax, o));

  float c_st[2][4], h_st[2][4];
  #pragma unroll
  for (int nt = 0; nt < 2; ++nt)
    #pragma unroll
    for (int r = 0; r < 4; ++r){ c_st[nt][r] = 0.0f; h_st[nt][r] = 0.0f; }

  short8 xcur[2], xnxt[2];
  #pragma unroll
  for (int nt = 0; nt < 2; ++nt){
    short8 xf = {0, 0, 0, 0, 0, 0, 0, 0};
    if (lane < 16) xf = *(const short8*)sB[nt];
    xcur[nt] = xf;
  }

  __syncthreads();

  for (int step = 0; step < nmax; ++step){
    const int ns = min(step + 1, 63);
    #pragma unroll
    for (int nt = 0; nt < 2; ++nt){
      short8 xf = {0, 0, 0, 0, 0, 0, 0, 0};
      if (lane < 16) xf = *(const short8*)(sB[nt] + (size_t)ns * 8);
      xnxt[nt] = xf;
    }

    const u16* rHi = hHi[step & 1];
    const u16* rLo = hLo[step & 1];
    u16* wHi = hHi[(step + 1) & 1];
    u16* wLo = hLo[(step + 1) & 1];
    float4v acc[4][2];
    #pragma unroll
    for (int nt = 0; nt < 2; ++nt){
      const int hb = (nt * 16 + nlo) * 72 + quad * 8;
      short8 h0 = *(const short8*)&rHi[hb];
      short8 h1 = *(const short8*)&rHi[hb + 32];
      short8 l0 = *(const short8*)&rLo[hb];
      short8 l1 = *(const short8*)&rLo[hb + 32];
      #pragma unroll
      for (int g = 0; g < 4; ++g){
        float4v a = binit[g];
        a = MFMA16(aX[g], xcur[nt], a);
        a = MFMA16(aW[g][0], h0, a);
        a = MFMA16(aW[g][1], h1, a);
        a = MFMA16(aW[g][0], l0, a);
        a = MFMA16(aW[g][1], l1, a);
        acc[g][nt] = a;
      }
    }
    #pragma unroll
    for (int nt = 0; nt < 2; ++nt){
      const bool v = (step < n2[nt]);
      u16 hb4[4], lb4[4];
      #pragma unroll
      for (int r = 0; r < 4; ++r){
        float gi = acc[0][nt][r], gf = acc[1][nt][r], gg = acc[2][nt][r], go = acc[3][nt][r];
        float cn = sigm(gf) * c_st[nt][r] + sigm(gi) * tanh_f(gg);
        float hn = sigm(go) * tanh_f(cn);
        c_st[nt][r] = v ? cn : c_st[nt][r];
        h_st[nt][r] = v ? hn : h_st[nt][r];
        u16 hi = f2bf(h_st[nt][r]);
        float lo = h_st[nt][r] - bf2f(hi);
        hb4[r] = hi; lb4[r] = f2bf(lo);
      }
      const int off = (nt * 16 + nlo) * 72 + q * 16 + quad * 4;
      uint2 hw, lw;
      hw.x = (uint)hb4[0] | ((uint)hb4[1] << 16);
      hw.y = (uint)hb4[2] | ((uint)hb4[3] << 16);
      lw.x = (uint)lb4[0] | ((uint)lb4[1] << 16);
      lw.y = (uint)lb4[2] | ((uint)lb4[3] << 16);
      *(uint2*)&wHi[off] = hw;
      *(uint2*)&wLo[off] = lw;
    }
    #pragma unroll
    for (int nt = 0; nt < 2; ++nt) xcur[nt] = xnxt[nt];
    __syncthreads();
  }

  const u16* fHi = hHi[nmax & 1];
  const u16* fLo = hLo[nmax & 1];
  short8 aT[2];
  #pragma unroll
  for (int f = 0; f < 2; ++f){
    const float* wr = Wt + W_WTS + (q * 16 + nlo) * 64 + f * 32 + quad * 8;
    short8 a;
    #pragma unroll
    for (int j = 0; j < 8; ++j) a[j] = (short)f2bf(wr[j]);
    aT[f] = a;
  }
  float4v btsv = *(const float4v*)(Wt + W_BTS + q * 16 + quad * 4);
  #pragma unroll
  for (int nt = 0; nt < 2; ++nt){
    const int hb = (nt * 16 + nlo) * 72 + quad * 8;
    float4v a = btsv;
    a = MFMA16(aT[0], *(const short8*)&fHi[hb], a);
    a = MFMA16(aT[1], *(const short8*)&fHi[hb + 32], a);
    a = MFMA16(aT[0], *(const short8*)&fLo[hb], a);
    a = MFMA16(aT[1], *(const short8*)&fLo[hb + 32], a);
    u16 o4[4];
    #pragma unroll
    for (int r = 0; r < 4; ++r) o4[r] = f2bf(fmaxf(a[r], 0.0f));
    size_t oidx = ((size_t)(t * NB + bb2[nt])) * 128 + 64 + q * 16 + quad * 4;
    uint2 w;
    w.x = (uint)o4[0] | ((uint)o4[1] << 16);
    w.y = (uint)o4[2] | ((uint)o4[3] << 16);
    *(uint2*)&xpartT[oidx] = w;
  }
}

// ---------- kernel F: outer LSTM via MFMA (3 steps) + MLP; 32-batch tiles ----------
__global__ __launch_bounds__(256) void kfinalM(const float* __restrict__ WF,
                                               const u16* __restrict__ xpartT,
                                               const u16* __restrict__ zxp,
                                               const int* __restrict__ hist_len,
                                               void* __restrict__ out,
                                               const int* __restrict__ flag){
  __shared__ u16 hHi[32 * 72];
  __shared__ u16 hLo[32 * 72];
  __shared__ float x1T[32 * 68];
  const bool isbf = (*flag != 0);
  const int b0   = blockIdx.x * 32;
  const int lane = threadIdx.x & 63;
  const int q    = __builtin_amdgcn_readfirstlane((int)(threadIdx.x >> 6));
  const int nlo  = lane & 15;
  const int quad = lane >> 4;

  for (int i = threadIdx.x; i < 32 * 72; i += 256){ hHi[i] = 0; hLo[i] = 0; }

  const float* WO = WF + W_OUT;
  int hl2[2];
  #pragma unroll
  for (int nt = 0; nt < 2; ++nt) hl2[nt] = hist_len[b0 + nt * 16 + nlo];

  short8 aI[4][4], aH[4][2];
  float4v bi4[4];
  #pragma unroll
  for (int g = 0; g < 4; ++g){
    const int mrow = g * 64 + q * 16 + nlo;
    #pragma unroll
    for (int f = 0; f < 4; ++f){
      const float* w = WO + WO_WIHO + mrow * 128 + f * 32 + quad * 8;
      short8 a;
      #pragma unroll
      for (int j = 0; j < 8; ++j) a[j] = (short)f2bf(w[j]);
      aI[g][f] = a;
    }
    #pragma unroll
    for (int f = 0; f < 2; ++f){
      const float* w = WO + WO_WHHO + mrow * 64 + f * 32 + quad * 8;
      short8 a;
      #pragma unroll
      for (int j = 0; j < 8; ++j) a[j] = (short)f2bf(w[j]);
      aH[g][f] = a;
    }
    bi4[g] = *(const float4v*)(WO + WO_BSUM + g * 64 + q * 16 + quad * 4);
  }

  float c_st[2][4], h_st[2][4];
  #pragma unroll
  for (int nt = 0; nt < 2; ++nt)
    #pragma unroll
    for (int r = 0; r < 4; ++r){ c_st[nt][r] = 0.0f; h_st[nt][r] = 0.0f; }
  __syncthreads();

  for (int p = 0; p < 3; ++p){
    float4v acc[4][2];
    #pragma unroll
    for (int nt = 0; nt < 2; ++nt){
      const int bb = b0 + nt * 16 + nlo;
      const int tt = 2 - ((p - hl2[nt] + 2) % 3);
      const u16* xb = (tt > 0 && hl2[nt] < 2) ? (zxp + (tt - 1) * 128)
                                              : xpartT + ((size_t)(tt * NB + bb)) * 128;
      short8 xf[4];
      #pragma unroll
      for (int f = 0; f < 4; ++f) xf[f] = *(const short8*)(xb + f * 32 + quad * 8);
      const int hb = (nt * 16 + nlo) * 72 + quad * 8;
      short8 h0 = *(const short8*)&hHi[hb];
      short8 h1 = *(const short8*)&hHi[hb + 32];
      short8 l0 = *(const short8*)&hLo[hb];
      short8 l1 = *(const short8*)&hLo[hb + 32];
      #pragma unroll
      for (int g = 0; g < 4; ++g){
        float4v a = bi4[g];
        #pragma unroll
        for (int f = 0; f < 4; ++f) a = MFMA16(aI[g][f], xf[f], a);
        a = MFMA16(aH[g][0], h0, a);
        a = MFMA16(aH[g][1], h1, a);
        a = MFMA16(aH[g][0], l0, a);
        a = MFMA16(aH[g][1], l1, a);
        acc[g][nt] = a;
      }
    }
    __syncthreads();
    #pragma unroll
    for (int nt = 0; nt < 2; ++nt){
      const bool v = (p <= hl2[nt]);
      u16 hb4[4], lb4[4];
      #pragma unroll
      for (int r = 0; r < 4; ++r){
        float gi = acc[0][nt][r], gf = acc[1][nt][r], gg = acc[2][nt][r], go = acc[3][nt][r];
        float cn = sigm(gf) * c_st[nt][r] + sigm(gi) * tanh_f(gg);
        float hn = sigm(go) * tanh_f(cn);
        c_st[nt][r] = v ? cn : c_st[nt][r];
        h_st[nt][r] = v ? hn : h_st[nt][r];
        u16 hi = f2bf(h_st[nt][r]);
        float lo = h_st[nt][r] - bf2f(hi);
        hb4[r] = hi; lb4[r] = f2bf(lo);
      }
      const int off = (nt * 16 + nlo) * 72 + q * 16 + quad * 4;
      uint2 hw, lw;
      hw.x = (uint)hb4[0] | ((uint)hb4[1] << 16);
      hw.y = (uint)hb4[2] | ((uint)hb4[3] << 16);
      lw.x = (uint)lb4[0] | ((uint)lb4[1] << 16);
      lw.y = (uint)lb4[2] | ((uint)lb4[3] << 16);
      *(uint2*)&hHi[off] = hw;
      *(uint2*)&hLo[off] = lw;
    }
    __syncthreads();
  }

  short8 a1[2];
  #pragma unroll
  for (int f = 0; f < 2; ++f){
    const float* w = WO + WO_W1 + (q * 16 + nlo) * 64 + f * 32 + quad * 8;
    short8 a;
    #pragma unroll
    for (int j = 0; j < 8; ++j) a[j] = (short)f2bf(w[j]);
    a1[f] = a;
  }
  float4v b1v = *(const float4v*)(WO + WO_B1 + q * 16 + quad * 4);
  #pragma unroll
  for (int nt = 0; nt < 2; ++nt){
    const int hb = (nt * 16 + nlo) * 72 + quad * 8;
    float4v a = b1v;
    a = MFMA16(a1[0], *(const short8*)&hHi[hb], a);
    a = MFMA16(a1[1], *(const short8*)&hHi[hb + 32], a);
    a = MFMA16(a1[0], *(const short8*)&hLo[hb], a);
    a = MFMA16(a1[1], *(const short8*)&hLo[hb + 32], a);
    float4v rv;
    #pragma unroll
    for (int r = 0; r < 4; ++r) rv[r] = fmaxf(a[r], 0.0f);
    *(float4v*)&x1T[(nt * 16 + nlo) * 68 + q * 16 + quad * 4] = rv;
  }
  __syncthreads();

  const int bloc = threadIdx.x >> 3;       // 0..31
  const int r0 = threadIdx.x & 7;
  const float* w2 = WO + WO_W2;
  const float* b2 = WO + WO_B2;
  for (int r = r0; r < 9; r += 8){
    float acc = b2[r];
    const float* wr = w2 + r * 64;
    #pragma unroll
    for (int k = 0; k < 64; ++k) acc = fmaf(wr[k], x1T[bloc * 68 + k], acc);
    if (isbf) ((u16*)out)[(size_t)(b0 + bloc) * 9 + r] = f2bf(acc);
    else      ((float*)out)[(size_t)(b0 + bloc) * 9 + r] = acc;
  }
}

extern "C" void kernel_launch(void* const* d_in, const int* in_sizes, int n_in,
                              void* d_out, int out_size, void* d_ws, size_t ws_size,
                              hipStream_t stream){
  char* ws = (char*)d_ws;
  float* WF = (float*)ws;
  size_t off = ((size_t)WF_TOTAL * 4 + 255) & ~(size_t)255;
  u16* sTx = (u16*)(ws + off);    off += (size_t)3 * NB * 512 * 2;
  u16* xpartT = (u16*)(ws + off); off += (size_t)3 * NB * 128 * 2;
  int* nar = (int*)(ws + off);    off += (size_t)3 * NB * 4;
  int* flag = (int*)(ws + off);   off += 256;
  int* cnt  = (int*)(ws + off);   off += 256;
  int* ghist = (int*)(ws + off);  off += 3 * 65 * 4 + 64;
  int* offs = (int*)(ws + off);   off += 3 * 65 * 4 + 64;
  int* idx  = (int*)(ws + off);   off += (size_t)3 * NB * 4;
  u16* zxp  = (u16*)(ws + off);   off += 2 * 128 * 2;

  PtrTab P;
  for (int i = 0; i < 36; ++i) P.p[i] = d_in[i];

  SegTab S;
  int si = 0;
  for (int t = 0; t < 3; ++t){
    int base = 4 + 8 * t;
    int d = t * TW;
    S.s[si++] = { base + 2, -1,       0,     d + W_WIH,         1536 };
    S.s[si++] = { base + 3, -1,       0,     d + W_WHH,         8192 };
    S.s[si++] = { base + 3, -1,       8192,  d + W_WHH + 8192,  8192 };
    S.s[si++] = { base + 4, base + 5, 0,     d + W_BSUM,        256  };
    S.s[si++] = { base + 6, -1,       0,     d + W_WTS,         4096 };
    S.s[si++] = { base + 7, -1,       0,     d + W_BTS,         64   };
    S.s[si++] = { base + 0, -1,       0,     d + W_WOS,         448  };
    S.s[si++] = { base + 1, -1,       0,     d + W_BOS,         64   };
  }
  {
    int O = W_OUT;
    for (int k = 0; k < 4; ++k)
      S.s[si++] = { 28, -1, k * 8192, O + WO_WIHO + k * 8192, 8192 };
    S.s[si++] = { 29, -1, 0,    O + WO_WHHO,        8192 };
    S.s[si++] = { 29, -1, 8192, O + WO_WHHO + 8192, 8192 };
    S.s[si++] = { 30, 31, 0,    O + WO_BSUM,        256  };
    S.s[si++] = { 32, -1, 0,    O + WO_W1,          4096 };
    S.s[si++] = { 33, -1, 0,    O + WO_B1,          64   };
    S.s[si++] = { 34, -1, 0,    O + WO_W2,          576  };
    S.s[si++] = { 35, -1, 0,    O + WO_B2,          9    };
  }

  const int* hl_ptr = (const int*)d_in[3];

  kweights<<<dim3(35), 256, 0, stream>>>(P, S, WF, d_in[7], flag, ghist);
  kprep<<<dim3(NB / 4, 3), 256, 0, stream>>>(d_in[0], d_in[1], hl_ptr, WF, sTx, nar, xpartT, flag);
  khistG<<<dim3(16, 3), 256, 0, stream>>>(hl_ptr, nar, ghist);
  kscanG<<<dim3(1), 64, 0, stream>>>(ghist, offs, cnt);
  kscatG<<<dim3(16, 3), 256, 0, stream>>>(hl_ptr, nar, offs, idx);
  kmainM<<<dim3(257, 3), 256, 0, stream>>>(nar, WF, sTx, xpartT, idx, cnt, zxp);
  kfinalM<<<dim3(NB / 32), 256, 0, stream>>>(WF, xpartT, zxp, hl_ptr, d_out, flag);
}